// Round 9
// baseline (1076.279 us; speedup 1.0000x reference)
//
#include <hip/hip_runtime.h>
#include <math.h>
#include <stdint.h>

typedef unsigned long long u64;
typedef unsigned int u32;

#define NN 100000
#define CF 128
#define EE 800000

#define CAP 131072             // selected-edge capacity (true count <= 50000)

// ---- edge radix sort: u32 keys, 3 passes x 11 bits (radix 2048) ----
#define EBITS 11
#define ERADIX 2048
#define STILE 2048
#define NB_E 391               // 391*2048 = 800768 >= EE
#define SORT_N (NB_E * STILE)
// ---- member radix sort: u64 keys (cluster<<32)|node, 2 passes x 12 bits over cluster ----
#define MBITS 12
#define MRADIX 4096
#define NB_M 49                // 49*2048 = 100352 >= NN
#define MSORT_N (NB_M * STILE)
#define HISTG_LEN 800768       // max(ERADIX*NB_E, MRADIX*NB_M)

#define LB_TILE 2048           // lookback-scan tile: 256 threads x 8
#define LB_SLOT 392            // status entries per scan slot (max 391 blocks)
#define MCHUNK 16              // members per block in cluster-sum

// fixed-point scales (order-independent integer accumulation => bitwise determinism)
#define ZSCALE 4503599627370496.0   // 2^52 for softmax denominator (z in (0,1])
#define XSCALE 32768.0f             // 2^15 for new_x contributions
#define XINV   (1.0f / 32768.0f)

struct Sel { u32 prefix; u32 k; };

__device__ inline u64 encD(double v) {
  u64 u = (u64)__double_as_longlong(v);
  return u ^ ((u >> 63) ? ~0ULL : 0x8000000000000000ULL);
}
__device__ inline double decD(u64 u) {
  u ^= ((u >> 63) ? 0x8000000000000000ULL : ~0ULL);
  return __longlong_as_double((long long)u);
}

// ---------- per-node dot products p = x.W[:C], q = x.W[C:], f64 ----------
__global__ void k_pq(const float* __restrict__ x, const float* __restrict__ W,
                     double* __restrict__ p, double* __restrict__ q) {
  int node = blockIdx.x * 4 + (threadIdx.x >> 6);
  int lane = threadIdx.x & 63;
  if (node >= NN) return;
  const float* xr = x + (size_t)node * CF;
  double a = (double)xr[lane] * (double)W[lane] + (double)xr[lane + 64] * (double)W[lane + 64];
  double c = (double)xr[lane] * (double)W[CF + lane] + (double)xr[lane + 64] * (double)W[CF + lane + 64];
  for (int off = 32; off; off >>= 1) { a += __shfl_xor(a, off); c += __shfl_xor(c, off); }
  if (lane == 0) { p[node] = a; q[node] = c; }
}

// ---------- e = p[src]+q[dst]+b ; segment max into menc (exact, order-free) ----------
__global__ void k_em(const int* __restrict__ ei, const double* __restrict__ p,
                     const double* __restrict__ q, const float* __restrict__ bptr,
                     double* __restrict__ e, u64* __restrict__ menc) {
  int j = blockIdx.x * 256 + threadIdx.x;
  if (j >= EE) return;
  int s = ei[j], d = ei[EE + j];
  double ev = p[s] + q[d] + (double)bptr[0];
  e[j] = ev;
  atomicMax(&menc[d], encD(ev));
}

// ---------- z = exp(e-m[dst]) (in place) ; fixed-point segment sum ----------
__global__ void k_zs(const int* __restrict__ ei, double* __restrict__ e,
                     const u64* __restrict__ menc, u64* __restrict__ sdenFx) {
  int j = blockIdx.x * 256 + threadIdx.x;
  if (j >= EE) return;
  int d = ei[EE + j];
  double z = exp(e[j] - decD(menc[d]));
  e[j] = z;
  atomicAdd(&sdenFx[d], (u64)__double2ll_rn(z * ZSCALE));
}

// ---------- score = z/s[dst] + 0.5 -> f32 out (fully deterministic) ----------
// NOTE: z/s in (0,1] => score in (0.5, 1.5] => f32 top byte is ALWAYS 0x3F.
__global__ void k_score(const int* __restrict__ ei, const double* __restrict__ z,
                        const u64* __restrict__ sdenFx, float* __restrict__ outScore) {
  int j = blockIdx.x * 256 + threadIdx.x;
  if (j >= EE) return;
  int d = ei[EE + j];
  double s = (double)sdenFx[d] * (1.0 / ZSCALE);
  outScore[j] = (float)(z[j] / s + 0.5);
}

// ---------- radix select (two order statistics; top byte pre-resolved = 0x3F) ----------
__global__ void k_selInit(Sel* st, u32* hist, int k0, int k1) {
  int t = blockIdx.x * 256 + threadIdx.x;
  if (t == 0) { st[0].prefix = 0x3Fu; st[0].k = (u32)k0; st[1].prefix = 0x3Fu; st[1].k = (u32)k1; }
  if (t < 512) hist[t] = 0;
}

__global__ void k_selHist(const float* __restrict__ score, const Sel* __restrict__ st,
                          u32* __restrict__ hist, int shift) {
  __shared__ u32 h[512];
  for (int i = threadIdx.x; i < 512; i += 256) h[i] = 0;
  __syncthreads();
  u32 p0 = st[0].prefix, p1 = st[1].prefix;
  for (int j = blockIdx.x * 256 + threadIdx.x; j < EE; j += gridDim.x * 256) {
    u32 u = __float_as_uint(score[j]);
    u32 d = (u >> shift) & 255u;
    if ((u >> (shift + 8)) == p0) atomicAdd(&h[d], 1u);
    if ((u >> (shift + 8)) == p1) atomicAdd(&h[256 + d], 1u);
  }
  __syncthreads();
  for (int i = threadIdx.x; i < 512; i += 256) if (h[i]) atomicAdd(&hist[i], h[i]);
}

__global__ void k_selPick(Sel* st, u32* hist) {
  if (threadIdx.x == 0) {
    for (int sel = 0; sel < 2; sel++) {
      u32 k = st[sel].k, cum = 0;
      for (int b = 0; b < 256; b++) {
        u32 c = hist[sel * 256 + b];
        if (cum + c > k) { st[sel].prefix = (st[sel].prefix << 8) | (u32)b; st[sel].k = k - cum; break; }
        cum += c;
      }
    }
  }
  __syncthreads();
  for (int i = threadIdx.x; i < 512; i += blockDim.x) hist[i] = 0;
}

// numpy _lerp: t = a + (b-a)*frac  (t in [a,b) -> mask == strict top-k)
__global__ void k_t(const Sel* st, float* tval, float frac) {
  float a = __uint_as_float(st[0].prefix);
  float b = __uint_as_float(st[1].prefix);
  tval[0] = __fadd_rn(a, __fmul_rn(__fsub_rn(b, a), frac));
}

// ---------- mask -> compacted edge list + endpoint counts (block-agg atomic) ----------
__global__ void __launch_bounds__(1024) k_compact(
    const float* __restrict__ score, const float* __restrict__ tval,
    const int* __restrict__ ei, int* __restrict__ selCount,
    int* __restrict__ selSrc, int* __restrict__ selDst,
    float* __restrict__ selW, int* __restrict__ cnt) {
  __shared__ int wbase[16];
  int j = blockIdx.x * 1024 + threadIdx.x;
  int lane = threadIdx.x & 63;
  int wid = threadIdx.x >> 6;
  float sc = 0.0f;
  bool sel = false;
  if (j < EE) { sc = score[j]; sel = (sc > tval[0]); }
  u64 m = __ballot(sel);
  int wcnt = __popcll(m);
  int rank = __popcll(m & ((1ULL << lane) - 1ULL));
  if (lane == 0) wbase[wid] = wcnt;
  __syncthreads();
  if (threadIdx.x == 0) {
    int tot = 0;
#pragma unroll
    for (int w = 0; w < 16; w++) tot += wbase[w];
    int base = tot ? atomicAdd(selCount, tot) : 0;
#pragma unroll
    for (int w = 0; w < 16; w++) { int c = wbase[w]; wbase[w] = base; base += c; }
  }
  __syncthreads();
  if (sel) {
    int s = ei[j], d = ei[EE + j];
    int pos = wbase[wid] + rank;
    if (pos < CAP) { selSrc[pos] = s; selDst[pos] = d; selW[pos] = sc; }
    atomicAdd(&cnt[s], 1);
    atomicAdd(&cnt[d], 1);
  }
}

// ---------- connected components: lock-free union-find (validated round 7/8) ----------
__global__ void k_labelInit(int* parent) {
  int i = blockIdx.x * 256 + threadIdx.x;
  if (i < NN) parent[i] = i;
}

__device__ inline int uf_find(int* parent, int x) {
  while (true) {
    int p = parent[x];
    if (p == x) return x;
    int gp = parent[p];
    if (gp == p) return p;
    parent[x] = gp;           // path halving (benign race)
    x = gp;
  }
}

__global__ void k_ufUnion(const int* __restrict__ selSrc, const int* __restrict__ selDst,
                          const int* __restrict__ selCount, int* __restrict__ parent) {
  int n = selCount[0]; if (n > CAP) n = CAP;
  for (int e = blockIdx.x * 256 + threadIdx.x; e < n; e += gridDim.x * 256) {
    int ru = uf_find(parent, selSrc[e]);
    int rv = uf_find(parent, selDst[e]);
    while (ru != rv) {
      if (ru < rv) { int t = ru; ru = rv; rv = t; }
      int old = atomicCAS(&parent[ru], ru, rv);
      if (old == ru) break;
      ru = uf_find(parent, old);
      rv = uf_find(parent, rv);
    }
  }
}

// flatten + emit root flags (fused)
__global__ void k_ufFlattenRoots(int* __restrict__ parent, int* __restrict__ roots) {
  int i = blockIdx.x * 256 + threadIdx.x;
  if (i >= NN) return;
  int x = i;
  while (true) { int p = parent[x]; if (p == x) break; x = p; }
  parent[i] = x;
  roots[i] = (x == i) ? 1 : 0;
}

// cluster id + member sort key (fused): key = (cluster<<32)|node
__global__ void k_clusterMkeys(const int* __restrict__ labels, const int* __restrict__ rootScan,
                               int* __restrict__ cluster, u64* __restrict__ mkeys) {
  int i = blockIdx.x * 256 + threadIdx.x;
  if (i < NN) {
    int cl = rootScan[labels[i]];
    cluster[i] = cl;
    mkeys[i] = ((u64)(u32)cl << 32) | (u32)i;
  } else if (i < MSORT_N) {
    mkeys[i] = ~0ULL;
  }
}

// ---------- single-kernel exclusive scan: decoupled lookback ----------
// status[b]: bits[1:0] 0=empty 1=aggregate 2=inclusive-prefix; bits[33:2]=value
__global__ void k_lbScan(const int* __restrict__ src, int* __restrict__ dst, int n,
                         u64* __restrict__ status, int* __restrict__ ticket) {
  __shared__ int sTile[256];
  __shared__ int sBid;
  __shared__ int sPrev;
  if (threadIdx.x == 0) sBid = atomicAdd(ticket, 1);
  __syncthreads();
  int bid = sBid;
  int base = bid * LB_TILE + threadIdx.x * 8;
  int v[8]; int s = 0;
#pragma unroll
  for (int i = 0; i < 8; i++) { v[i] = (base + i < n) ? src[base + i] : 0; s += v[i]; }
  sTile[threadIdx.x] = s;
  __syncthreads();
  for (int off = 1; off < 256; off <<= 1) {
    int t = (threadIdx.x >= off) ? sTile[threadIdx.x - off] : 0;
    __syncthreads();
    sTile[threadIdx.x] += t;
    __syncthreads();
  }
  int total = sTile[255];
  int runBase = sTile[threadIdx.x] - s;
  if (threadIdx.x == 0) {
    if (bid == 0) {
      __hip_atomic_store(&status[0], (((u64)(u32)total) << 2) | 2ULL,
                         __ATOMIC_RELEASE, __HIP_MEMORY_SCOPE_AGENT);
      sPrev = 0;
    } else {
      __hip_atomic_store(&status[bid], (((u64)(u32)total) << 2) | 1ULL,
                         __ATOMIC_RELEASE, __HIP_MEMORY_SCOPE_AGENT);
      int prev = 0;
      int j = bid - 1;
      while (true) {
        u64 stv = __hip_atomic_load(&status[j], __ATOMIC_ACQUIRE, __HIP_MEMORY_SCOPE_AGENT);
        u32 state = (u32)(stv & 3ULL);
        if (state == 0) { __builtin_amdgcn_s_sleep(1); continue; }
        prev += (int)(u32)(stv >> 2);
        if (state == 2) break;
        j--;
      }
      __hip_atomic_store(&status[bid], (((u64)(u32)(prev + total)) << 2) | 2ULL,
                         __ATOMIC_RELEASE, __HIP_MEMORY_SCOPE_AGENT);
      sPrev = prev;
    }
  }
  __syncthreads();
  int run = sPrev + runBase;
#pragma unroll
  for (int i = 0; i < 8; i++) { int vv = v[i]; if (base + i < n) dst[base + i] = run; run += vv; }
}

// ---------- radix sort (templated key type + digit width) ----------
template <typename K, int BITS>
__global__ void k_sortHistT(const K* __restrict__ keys, int* __restrict__ hist,
                            int shift, int nb) {
  const int RAD = 1 << BITS;
  __shared__ int h[RAD];
  for (int i = threadIdx.x; i < RAD; i += 256) h[i] = 0;
  __syncthreads();
  int base = blockIdx.x * STILE;
  for (int i = threadIdx.x; i < STILE; i += 256) {
    int d = (int)((keys[base + i] >> shift) & (RAD - 1));
    atomicAdd(&h[d], 1);
  }
  __syncthreads();
  for (int i = threadIdx.x; i < RAD; i += 256) hist[i * nb + blockIdx.x] = h[i];
}

template <typename K, int BITS>
__global__ void k_sortScatterT(const K* __restrict__ in, K* __restrict__ out,
                               const int* __restrict__ histScanned, int shift, int nb) {
  const int RAD = 1 << BITS;
  __shared__ int run[RAD];
  for (int i = threadIdx.x; i < RAD; i += 256) run[i] = 0;
  __syncthreads();
  int lane = threadIdx.x & 63;
  int wid = threadIdx.x >> 6;
  int base = blockIdx.x * STILE;
  for (int chunk = 0; chunk < 8; chunk++) {
    K key = in[base + chunk * 256 + threadIdx.x];
    int d = (int)((key >> shift) & (RAD - 1));
    u64 m = ~0ULL;
#pragma unroll
    for (int b = 0; b < BITS; b++) {
      u64 bal = __ballot((d >> b) & 1);
      m &= ((d >> b) & 1) ? bal : ~bal;
    }
    int laneRank = __popcll(m & ((1ULL << lane) - 1ULL));
    int cntm = __popcll(m);
    bool leader = (laneRank == 0);
    int local = 0;
    for (int w = 0; w < 4; w++) {
      if (wid == w) {
        int basev = run[d];
        local = basev + laneRank;
        if (leader) run[d] = basev + cntm;
      }
      __syncthreads();
    }
    out[histScanned[d * nb + blockIdx.x] + local] = key;
  }
}

// ---------- CSR of selected edges per node ----------
__global__ void k_csr(const int* __restrict__ selSrc, const int* __restrict__ selDst,
                      const int* __restrict__ selCount, const int* __restrict__ nodeOff,
                      int* __restrict__ fill, int* __restrict__ edgeIdx) {
  int n = selCount[0]; if (n > CAP) n = CAP;
  for (int e = blockIdx.x * 256 + threadIdx.x; e < n; e += gridDim.x * 256) {
    int s = selSrc[e];
    int p = atomicAdd(&fill[s], 1);
    edgeIdx[nodeOff[s] + p] = e;
    int d = selDst[e];
    int p2 = atomicAdd(&fill[d], 1);
    edgeIdx[nodeOff[d] + p2] = e;
  }
}

// ---------- cluster sum: gather per node, run-flush per cluster ----------
// cnt==0 members skipped entirely (singleton clusters handled by k_copyUntouched).
__global__ void __launch_bounds__(128) k_clusterSum(
    const u64* __restrict__ mk, const int* __restrict__ nodeOff, const int* __restrict__ cnt,
    const int* __restrict__ edgeIdx, const int* __restrict__ selSrc,
    const int* __restrict__ selDst, const float* __restrict__ selW,
    const float* __restrict__ x, int* __restrict__ accX) {
  int c = threadIdx.x;               // channel 0..127
  int base = blockIdx.x * MCHUNK;
  if (base >= NN) return;
  int end = base + MCHUNK; if (end > NN) end = NN;
  u64 k0 = mk[base];
  int clN = (int)(k0 >> 32);
  int nodeN = (int)(k0 & 0xFFFFFFFFULL);
  int cntN = cnt[nodeN];
  int offN = nodeOff[nodeN];
  int curCl = -1; int acc = 0;
  for (int m = base; m < end; m++) {
    int cl = clN, ci = cntN, o = offN;
    if (m + 1 < end) {
      u64 k1 = mk[m + 1];
      clN = (int)(k1 >> 32);
      nodeN = (int)(k1 & 0xFFFFFFFFULL);
      cntN = cnt[nodeN];
      offN = nodeOff[nodeN];
    }
    if (ci == 0) continue;           // singleton untouched: exact copy path elsewhere
    if (cl != curCl) {
      if (curCl >= 0 && acc != 0) atomicAdd(&accX[(size_t)curCl * CF + c], acc);
      curCl = cl; acc = 0;
    }
    int eN = edgeIdx[o];
    for (int t = 0; t < ci; t++) {
      int e = eN;
      if (t + 1 < ci) eN = edgeIdx[o + t + 1];
      float r = (x[(size_t)selSrc[e] * CF + c] + x[(size_t)selDst[e] * CF + c]) * selW[e];
      acc += __float2int_rn((r / (float)ci) * XSCALE);  // same rounding as validated kernel
    }
  }
  if (curCl >= 0 && acc != 0) atomicAdd(&accX[(size_t)curCl * CF + c], acc);
}

// ---------- finalize: int fixed -> f32 (vectorized) ----------
__global__ void k_final2(const int* __restrict__ accX, float* __restrict__ outNewX) {
  int t = (blockIdx.x * 256 + threadIdx.x) * 4;
  if (t >= NN * CF) return;
  int4 v = *(const int4*)(accX + t);
  float4 o;
  o.x = (float)v.x * XINV; o.y = (float)v.y * XINV;
  o.z = (float)v.z * XINV; o.w = (float)v.w * XINV;
  *(float4*)(outNewX + t) = o;
}

// untouched nodes (cnt==0, singleton clusters): exact f32 copy of their x row
__global__ void k_copyUntouched(const float* __restrict__ x, const int* __restrict__ cnt,
                                const int* __restrict__ cluster, float* __restrict__ outNewX) {
  int t = blockIdx.x * 256 + threadIdx.x;
  if (t >= NN * CF) return;
  int i = t >> 7; int c = t & 127;
  if (cnt[i] == 0) outNewX[(size_t)cluster[i] * CF + c] = x[t];
}

// ---------- edge coalescing: int32-WRAPPED u32 keys (JAX x64-disabled semantics) ----------
__global__ void k_keysInit(const int* __restrict__ ei, const int* __restrict__ cluster,
                           u32* __restrict__ keys) {
  int t = blockIdx.x * 256 + threadIdx.x;
  if (t >= SORT_N) return;
  if (t < EE) {
    u32 kw = (u32)cluster[ei[t]] * 100000u + (u32)cluster[ei[EE + t]];  // int32 wraparound
    keys[t] = kw ^ 0x80000000u;   // bias: unsigned order == signed order
  } else {
    keys[t] = 0xFFFFFFFFu;        // pads sort to the tail
  }
}

__global__ void k_eiFill(float* __restrict__ outEI) {
  int t = blockIdx.x * 256 + threadIdx.x;
  if (t < 2 * EE) outEI[t] = -1.0f;
}

// fused: unique flags + lookback scan + scatter of coalesced edges
__global__ void k_eiUnique(const u32* __restrict__ keys, u64* __restrict__ status,
                           int* __restrict__ ticket, float* __restrict__ outEI) {
  __shared__ int sTile[256];
  __shared__ int sBid;
  __shared__ int sPrev;
  if (threadIdx.x == 0) sBid = atomicAdd(ticket, 1);
  __syncthreads();
  int bid = sBid;
  int base = bid * LB_TILE + threadIdx.x * 8;
  int f[8]; int s = 0;
  u32 kv[8];
#pragma unroll
  for (int i = 0; i < 8; i++) {
    int j = base + i;
    if (j < EE) {
      kv[i] = keys[j];
      u32 prevk = (i > 0) ? kv[i - 1] : ((j > 0) ? keys[j - 1] : (kv[i] + 1u));
      f[i] = (j == 0 || kv[i] != prevk) ? 1 : 0;
    } else { kv[i] = 0; f[i] = 0; }
    s += f[i];
  }
  sTile[threadIdx.x] = s;
  __syncthreads();
  for (int off = 1; off < 256; off <<= 1) {
    int t = (threadIdx.x >= off) ? sTile[threadIdx.x - off] : 0;
    __syncthreads();
    sTile[threadIdx.x] += t;
    __syncthreads();
  }
  int total = sTile[255];
  int runBase = sTile[threadIdx.x] - s;
  if (threadIdx.x == 0) {
    if (bid == 0) {
      __hip_atomic_store(&status[0], (((u64)(u32)total) << 2) | 2ULL,
                         __ATOMIC_RELEASE, __HIP_MEMORY_SCOPE_AGENT);
      sPrev = 0;
    } else {
      __hip_atomic_store(&status[bid], (((u64)(u32)total) << 2) | 1ULL,
                         __ATOMIC_RELEASE, __HIP_MEMORY_SCOPE_AGENT);
      int prev = 0;
      int j = bid - 1;
      while (true) {
        u64 stv = __hip_atomic_load(&status[j], __ATOMIC_ACQUIRE, __HIP_MEMORY_SCOPE_AGENT);
        u32 state = (u32)(stv & 3ULL);
        if (state == 0) { __builtin_amdgcn_s_sleep(1); continue; }
        prev += (int)(u32)(stv >> 2);
        if (state == 2) break;
        j--;
      }
      __hip_atomic_store(&status[bid], (((u64)(u32)(prev + total)) << 2) | 2ULL,
                         __ATOMIC_RELEASE, __HIP_MEMORY_SCOPE_AGENT);
      sPrev = prev;
    }
  }
  __syncthreads();
  int run = sPrev + runBase;
#pragma unroll
  for (int i = 0; i < 8; i++) {
    if (f[i]) {
      int k32 = (int)(kv[i] ^ 0x80000000u);  // unbias -> wrapped int32 key
      if (k32 >= 0) {                         // ref: valid = keys >= 0
        outEI[run] = (float)(k32 / 100000);
        outEI[EE + run] = (float)(k32 % 100000);
      }
      run++;
    }
  }
}

// ---------------------------------------------------------------------------

extern "C" void kernel_launch(void* const* d_in, const int* in_sizes, int n_in,
                              void* d_out, int out_size, void* d_ws, size_t ws_size,
                              hipStream_t stream) {
  const float* x = (const float*)d_in[0];
  const int* ei = (const int*)d_in[1];
  // d_in[2] = batch (all zeros, unused)
  const float* W = (const float*)d_in[3];
  const float* bptr = (const float*)d_in[4];

  // ---- workspace carve-up (256B aligned) ----
  char* wp = (char*)d_ws;
  auto alloc = [&](size_t bytes) -> void* {
    void* r = (void*)wp;
    wp += (bytes + 255) & ~(size_t)255;
    return r;
  };
  // Overlay region (all dead before accX memset):
  double* ez = (double*)alloc((size_t)EE * 8);           // 6.4 MB
  u32* sortA = (u32*)alloc((size_t)SORT_N * 4);          // 3.2 MB
  u32* sortB = (u32*)alloc((size_t)SORT_N * 4);          // 3.2 MB
  int* histG = (int*)alloc((size_t)HISTG_LEN * 4);       // 3.2 MB
  int* roots = (int*)alloc((size_t)NN * 4);
  double* p_d = (double*)alloc((size_t)NN * 8);
  double* q_d = (double*)alloc((size_t)NN * 8);
  u64* menc = (u64*)alloc((size_t)NN * 8);               // zero region A start
  u64* sdenFx = (u64*)alloc((size_t)NN * 8);             // zero region A end
  char* zeroAEnd = wp;
  // accX (51.2MB) overlays everything above (~19MB)
  int* accX = (int*)d_ws;
  const size_t ACCX_BYTES = (size_t)NN * CF * 4;
  if (wp < (char*)d_ws + ACCX_BYTES) wp = (char*)d_ws + ACCX_BYTES;
  // Persistent:
  int* cnt = (int*)alloc((size_t)NN * 4);                // zero region B start
  int* fill = (int*)alloc((size_t)NN * 4);
  int* selCount = (int*)alloc(256);
  u64* lbStatus = (u64*)alloc((size_t)8 * LB_SLOT * 8);  // 8 scan slots
  int* lbTicket = (int*)alloc(8 * 4);                    // zero region B end
  char* zeroBStart = (char*)cnt; char* zeroBEnd = wp;
  int* nodeOff = (int*)alloc((size_t)NN * 4);
  int* selSrc = (int*)alloc((size_t)CAP * 4);
  int* selDst = (int*)alloc((size_t)CAP * 4);
  float* selW = (float*)alloc((size_t)CAP * 4);
  int* labels = (int*)alloc((size_t)NN * 4);
  int* cluster = (int*)alloc((size_t)NN * 4);
  int* edgeIdx = (int*)alloc((size_t)CAP * 4);
  u64* mA = (u64*)alloc((size_t)MSORT_N * 8);            // member sort (persistent)
  u64* mB = (u64*)alloc((size_t)MSORT_N * 8);
  Sel* st = (Sel*)alloc(256);
  u32* selHist = (u32*)alloc(512 * 4);
  float* tval = (float*)alloc(256);
  (void)ws_size; (void)n_in; (void)in_sizes;

  auto lbScan = [&](const int* src, int* dst, int n, int slot) {
    int nb = (n + LB_TILE - 1) / LB_TILE;
    k_lbScan<<<nb, 256, 0, stream>>>(src, dst, n, lbStatus + slot * LB_SLOT, lbTicket + slot);
  };

  // ---- output regions (all written as f32) ----
  float* outNewX = (float*)d_out;                       // N*C
  float* outEI = outNewX + (size_t)NN * CF;             // 2*E
  float* outBatch = outEI + 2 * (size_t)EE;             // N (zeros via memset)
  float* outScore = outBatch + NN;                      // E

  // ---- quantile index/weights (np.quantile: virtual index) ----
  double qd = 1.0 - (double)(NN / 2) / (double)EE;      // 0.9375 exact
  double posd = qd * (double)(EE - 1);                  // 749999.0625 exact
  int k0 = (int)floor(posd);
  double fracd = posd - floor(posd);                    // 0.0625 exact
  int k1 = (fracd > 0.0) ? k0 + 1 : k0;
  float frac = (float)fracd;

  // ---- init ----
  hipMemsetAsync(outBatch, 0, (size_t)NN * 4, stream);
  hipMemsetAsync(menc, 0, (size_t)(zeroAEnd - (char*)menc), stream);
  hipMemsetAsync(zeroBStart, 0, (size_t)(zeroBEnd - zeroBStart), stream);

  // ---- scores (deterministic: f64 math + exact max + fixed-point denom) ----
  k_pq<<<(NN + 3) / 4, 256, 0, stream>>>(x, W, p_d, q_d);
  k_em<<<(EE + 255) / 256, 256, 0, stream>>>(ei, p_d, q_d, bptr, ez, menc);
  k_zs<<<(EE + 255) / 256, 256, 0, stream>>>(ei, ez, menc, sdenFx);
  k_score<<<(EE + 255) / 256, 256, 0, stream>>>(ei, ez, sdenFx, outScore);

  // ---- quantile via radix select (3 passes; top byte known = 0x3F) ----
  k_selInit<<<2, 256, 0, stream>>>(st, selHist, k0, k1);
  for (int pass = 0; pass < 3; pass++) {
    k_selHist<<<1024, 256, 0, stream>>>(outScore, st, selHist, 16 - 8 * pass);
    k_selPick<<<1, 256, 0, stream>>>(st, selHist);
  }
  k_t<<<1, 64, 0, stream>>>(st, tval, frac);

  // ---- mask -> compacted edges + endpoint counts ----
  k_compact<<<(EE + 1023) / 1024, 1024, 0, stream>>>(outScore, tval, ei, selCount,
                                                     selSrc, selDst, selW, cnt);

  // ---- connected components: lock-free union-find ----
  k_labelInit<<<(NN + 255) / 256, 256, 0, stream>>>(labels);
  k_ufUnion<<<256, 256, 0, stream>>>(selSrc, selDst, selCount, labels);
  k_ufUnion<<<256, 256, 0, stream>>>(selSrc, selDst, selCount, labels);  // belt-and-braces
  k_ufFlattenRoots<<<(NN + 255) / 256, 256, 0, stream>>>(labels, roots);

  // ---- relabel by rank of component-min; emit member sort keys fused ----
  lbScan(roots, roots, NN, 0);
  k_clusterMkeys<<<(MSORT_N + 255) / 256, 256, 0, stream>>>(labels, roots, cluster, mA);

  // ---- member sort: 2 passes over cluster bits (node order stable-preserved) ----
  {
    u64* msin = mA; u64* msout = mB;
    for (int pass = 0; pass < 2; pass++) {
      int shift = 32 + MBITS * pass;
      k_sortHistT<u64, MBITS><<<NB_M, 256, 0, stream>>>(msin, histG, shift, NB_M);
      lbScan(histG, histG, MRADIX * NB_M, 1 + pass);
      k_sortScatterT<u64, MBITS><<<NB_M, 256, 0, stream>>>(msin, msout, histG, shift, NB_M);
      u64* tmp = msin; msin = msout; msout = tmp;
    }
    // result in mA (persistent)
  }
  u64* memberKeys = mA;

  // ---- coalesced cluster edges: u32 keys, 3 x 11-bit passes ----
  k_keysInit<<<SORT_N / 256, 256, 0, stream>>>(ei, cluster, sortA);
  u32* sin = sortA; u32* sout = sortB;
  for (int pass = 0; pass < 3; pass++) {
    int shift = EBITS * pass;
    k_sortHistT<u32, EBITS><<<NB_E, 256, 0, stream>>>(sin, histG, shift, NB_E);
    lbScan(histG, histG, ERADIX * NB_E, 3 + pass);
    k_sortScatterT<u32, EBITS><<<NB_E, 256, 0, stream>>>(sin, sout, histG, shift, NB_E);
    u32* tmp = sin; sin = sout; sout = tmp;
  }
  // result in sortB (== sin)
  k_eiFill<<<(2 * EE + 255) / 256, 256, 0, stream>>>(outEI);
  {
    int nb = (EE + LB_TILE - 1) / LB_TILE;
    k_eiUnique<<<nb, 256, 0, stream>>>(sin, lbStatus + 6 * LB_SLOT, lbTicket + 6, outEI);
  }

  // ---- node CSR (nodeOff = exclusive scan of cnt) ----
  lbScan(cnt, nodeOff, NN, 7);
  k_csr<<<256, 256, 0, stream>>>(selSrc, selDst, selCount, nodeOff, fill, edgeIdx);

  // ---- new_x: gather per node, run-flush per cluster (overlay now safe) ----
  hipMemsetAsync(accX, 0, ACCX_BYTES, stream);
  k_clusterSum<<<(NN + MCHUNK - 1) / MCHUNK, 128, 0, stream>>>(
      memberKeys, nodeOff, cnt, edgeIdx, selSrc, selDst, selW, x, accX);
  k_final2<<<(NN * CF / 4 + 255) / 256, 256, 0, stream>>>(accX, outNewX);
  k_copyUntouched<<<(NN * CF + 255) / 256, 256, 0, stream>>>(x, cnt, cluster, outNewX);
}

// Round 10
// 703.029 us; speedup vs baseline: 1.5309x; 1.5309x over previous
//
#include <hip/hip_runtime.h>
#include <math.h>
#include <stdint.h>

typedef unsigned long long u64;
typedef unsigned int u32;

#define NN 100000
#define CF 128
#define EE 800000

#define CAP 131072             // selected-edge capacity (true count <= 50000)

// ---- edge radix sort: u32 keys, 3 passes x 11 bits (radix 2048) ----
#define EBITS 11
#define ERADIX 2048
#define STILE 2048
#define NB_E 391               // 391*2048 = 800768 >= EE
#define SORT_N (NB_E * STILE)
// ---- member radix sort: u64 keys (cluster<<32)|node, 2 passes x 12 bits over cluster ----
#define MBITS 12
#define MRADIX 4096
#define NB_M 49                // 49*2048 = 100352 >= NN
#define MSORT_N (NB_M * STILE)
#define HISTG_LEN 800768       // max(ERADIX*NB_E, MRADIX*NB_M)

#define SCTILE 2048            // scan tile: 256 threads x 8
#define MCHUNK 16              // members per block in cluster-sum

// fixed-point scales (order-independent integer accumulation => bitwise determinism)
#define ZSCALE 4503599627370496.0   // 2^52 for softmax denominator (z in (0,1])
#define XSCALE 32768.0f             // 2^15 for new_x contributions
#define XINV   (1.0f / 32768.0f)

struct Sel { u32 prefix; u32 k; };

__device__ inline u64 encD(double v) {
  u64 u = (u64)__double_as_longlong(v);
  return u ^ ((u >> 63) ? ~0ULL : 0x8000000000000000ULL);
}
__device__ inline double decD(u64 u) {
  u ^= ((u >> 63) ? 0x8000000000000000ULL : ~0ULL);
  return __longlong_as_double((long long)u);
}

// ---------- per-node dot products p = x.W[:C], q = x.W[C:], f64 ----------
__global__ void k_pq(const float* __restrict__ x, const float* __restrict__ W,
                     double* __restrict__ p, double* __restrict__ q) {
  int node = blockIdx.x * 4 + (threadIdx.x >> 6);
  int lane = threadIdx.x & 63;
  if (node >= NN) return;
  const float* xr = x + (size_t)node * CF;
  double a = (double)xr[lane] * (double)W[lane] + (double)xr[lane + 64] * (double)W[lane + 64];
  double c = (double)xr[lane] * (double)W[CF + lane] + (double)xr[lane + 64] * (double)W[CF + lane + 64];
  for (int off = 32; off; off >>= 1) { a += __shfl_xor(a, off); c += __shfl_xor(c, off); }
  if (lane == 0) { p[node] = a; q[node] = c; }
}

// ---------- e = p[src]+q[dst]+b ; segment max into menc (exact, order-free) ----------
__global__ void k_em(const int* __restrict__ ei, const double* __restrict__ p,
                     const double* __restrict__ q, const float* __restrict__ bptr,
                     double* __restrict__ e, u64* __restrict__ menc) {
  int j = blockIdx.x * 256 + threadIdx.x;
  if (j >= EE) return;
  int s = ei[j], d = ei[EE + j];
  double ev = p[s] + q[d] + (double)bptr[0];
  e[j] = ev;
  atomicMax(&menc[d], encD(ev));
}

// ---------- z = exp(e-m[dst]) (in place) ; fixed-point segment sum ----------
__global__ void k_zs(const int* __restrict__ ei, double* __restrict__ e,
                     const u64* __restrict__ menc, u64* __restrict__ sdenFx) {
  int j = blockIdx.x * 256 + threadIdx.x;
  if (j >= EE) return;
  int d = ei[EE + j];
  double z = exp(e[j] - decD(menc[d]));
  e[j] = z;
  atomicAdd(&sdenFx[d], (u64)__double2ll_rn(z * ZSCALE));
}

// ---------- score = z/s[dst] + 0.5 -> f32 out (fully deterministic) ----------
// NOTE: z/s in (0,1] => score in (0.5, 1.5] => f32 top byte is ALWAYS 0x3F.
__global__ void k_score(const int* __restrict__ ei, const double* __restrict__ z,
                        const u64* __restrict__ sdenFx, float* __restrict__ outScore) {
  int j = blockIdx.x * 256 + threadIdx.x;
  if (j >= EE) return;
  int d = ei[EE + j];
  double s = (double)sdenFx[d] * (1.0 / ZSCALE);
  outScore[j] = (float)(z[j] / s + 0.5);
}

// ---------- radix select (two order statistics; top byte pre-resolved = 0x3F) ----------
__global__ void k_selInit(Sel* st, u32* hist, int k0, int k1) {
  int t = blockIdx.x * 256 + threadIdx.x;
  if (t == 0) { st[0].prefix = 0x3Fu; st[0].k = (u32)k0; st[1].prefix = 0x3Fu; st[1].k = (u32)k1; }
  if (t < 512) hist[t] = 0;
}

__global__ void k_selHist(const float* __restrict__ score, const Sel* __restrict__ st,
                          u32* __restrict__ hist, int shift) {
  __shared__ u32 h[512];
  for (int i = threadIdx.x; i < 512; i += 256) h[i] = 0;
  __syncthreads();
  u32 p0 = st[0].prefix, p1 = st[1].prefix;
  for (int j = blockIdx.x * 256 + threadIdx.x; j < EE; j += gridDim.x * 256) {
    u32 u = __float_as_uint(score[j]);
    u32 d = (u >> shift) & 255u;
    if ((u >> (shift + 8)) == p0) atomicAdd(&h[d], 1u);
    if ((u >> (shift + 8)) == p1) atomicAdd(&h[256 + d], 1u);
  }
  __syncthreads();
  for (int i = threadIdx.x; i < 512; i += 256) if (h[i]) atomicAdd(&hist[i], h[i]);
}

__global__ void k_selPick(Sel* st, u32* hist) {
  if (threadIdx.x == 0) {
    for (int sel = 0; sel < 2; sel++) {
      u32 k = st[sel].k, cum = 0;
      for (int b = 0; b < 256; b++) {
        u32 c = hist[sel * 256 + b];
        if (cum + c > k) { st[sel].prefix = (st[sel].prefix << 8) | (u32)b; st[sel].k = k - cum; break; }
        cum += c;
      }
    }
  }
  __syncthreads();
  for (int i = threadIdx.x; i < 512; i += blockDim.x) hist[i] = 0;
}

// numpy _lerp: t = a + (b-a)*frac  (t in [a,b) -> mask == strict top-k)
__global__ void k_t(const Sel* st, float* tval, float frac) {
  float a = __uint_as_float(st[0].prefix);
  float b = __uint_as_float(st[1].prefix);
  tval[0] = __fadd_rn(a, __fmul_rn(__fsub_rn(b, a), frac));
}

// ---------- mask -> compacted edge list + endpoint counts (block-agg atomic) ----------
__global__ void __launch_bounds__(1024) k_compact(
    const float* __restrict__ score, const float* __restrict__ tval,
    const int* __restrict__ ei, int* __restrict__ selCount,
    int* __restrict__ selSrc, int* __restrict__ selDst,
    float* __restrict__ selW, int* __restrict__ cnt) {
  __shared__ int wbase[16];
  int j = blockIdx.x * 1024 + threadIdx.x;
  int lane = threadIdx.x & 63;
  int wid = threadIdx.x >> 6;
  float sc = 0.0f;
  bool sel = false;
  if (j < EE) { sc = score[j]; sel = (sc > tval[0]); }
  u64 m = __ballot(sel);
  int wcnt = __popcll(m);
  int rank = __popcll(m & ((1ULL << lane) - 1ULL));
  if (lane == 0) wbase[wid] = wcnt;
  __syncthreads();
  if (threadIdx.x == 0) {
    int tot = 0;
#pragma unroll
    for (int w = 0; w < 16; w++) tot += wbase[w];
    int base = tot ? atomicAdd(selCount, tot) : 0;
#pragma unroll
    for (int w = 0; w < 16; w++) { int c = wbase[w]; wbase[w] = base; base += c; }
  }
  __syncthreads();
  if (sel) {
    int s = ei[j], d = ei[EE + j];
    int pos = wbase[wid] + rank;
    if (pos < CAP) { selSrc[pos] = s; selDst[pos] = d; selW[pos] = sc; }
    atomicAdd(&cnt[s], 1);
    atomicAdd(&cnt[d], 1);
  }
}

// ---------- connected components: lock-free union-find (validated r7/r8/r9) ----------
__global__ void k_labelInit(int* parent) {
  int i = blockIdx.x * 256 + threadIdx.x;
  if (i < NN) parent[i] = i;
}

__device__ inline int uf_find(int* parent, int x) {
  while (true) {
    int p = parent[x];
    if (p == x) return x;
    int gp = parent[p];
    if (gp == p) return p;
    parent[x] = gp;           // path halving (benign race)
    x = gp;
  }
}

__global__ void k_ufUnion(const int* __restrict__ selSrc, const int* __restrict__ selDst,
                          const int* __restrict__ selCount, int* __restrict__ parent) {
  int n = selCount[0]; if (n > CAP) n = CAP;
  for (int e = blockIdx.x * 256 + threadIdx.x; e < n; e += gridDim.x * 256) {
    int ru = uf_find(parent, selSrc[e]);
    int rv = uf_find(parent, selDst[e]);
    while (ru != rv) {
      if (ru < rv) { int t = ru; ru = rv; rv = t; }
      int old = atomicCAS(&parent[ru], ru, rv);
      if (old == ru) break;
      ru = uf_find(parent, old);
      rv = uf_find(parent, rv);
    }
  }
}

// flatten + emit root flags (fused)
__global__ void k_ufFlattenRoots(int* __restrict__ parent, int* __restrict__ roots) {
  int i = blockIdx.x * 256 + threadIdx.x;
  if (i >= NN) return;
  int x = i;
  while (true) { int p = parent[x]; if (p == x) break; x = p; }
  parent[i] = x;
  roots[i] = (x == i) ? 1 : 0;
}

// cluster id + member sort key (fused): key = (cluster<<32)|node
__global__ void k_clusterMkeys(const int* __restrict__ labels, const int* __restrict__ rootScan,
                               int* __restrict__ cluster, u64* __restrict__ mkeys) {
  int i = blockIdx.x * 256 + threadIdx.x;
  if (i < NN) {
    int cl = rootScan[labels[i]];
    cluster[i] = cl;
    mkeys[i] = ((u64)(u32)cl << 32) | (u32)i;
  } else if (i < MSORT_N) {
    mkeys[i] = ~0ULL;
  }
}

// ---------- generic exclusive scan (3-launch, validated) ----------
__global__ void k_scanBlock(const int* __restrict__ src, int* __restrict__ dst,
                            int n, int* __restrict__ bsums) {
  __shared__ int part[256];
  int base = blockIdx.x * SCTILE + threadIdx.x * 8;
  int v[8]; int s = 0;
#pragma unroll
  for (int i = 0; i < 8; i++) { v[i] = (base + i < n) ? src[base + i] : 0; s += v[i]; }
  part[threadIdx.x] = s;
  __syncthreads();
  for (int off = 1; off < 256; off <<= 1) {
    int t = (threadIdx.x >= off) ? part[threadIdx.x - off] : 0;
    __syncthreads();
    part[threadIdx.x] += t;
    __syncthreads();
  }
  int run = part[threadIdx.x] - s;
#pragma unroll
  for (int i = 0; i < 8; i++) { int vv = v[i]; if (base + i < n) dst[base + i] = run; run += vv; }
  if (threadIdx.x == 255) bsums[blockIdx.x] = part[255];
}
__global__ void k_scanTop(int* __restrict__ bsums, int nb) {
  __shared__ int part[256];
  int base = threadIdx.x * 4;
  int v[4]; int s = 0;
#pragma unroll
  for (int i = 0; i < 4; i++) { v[i] = (base + i < nb) ? bsums[base + i] : 0; s += v[i]; }
  part[threadIdx.x] = s;
  __syncthreads();
  for (int off = 1; off < 256; off <<= 1) {
    int t = (threadIdx.x >= off) ? part[threadIdx.x - off] : 0;
    __syncthreads();
    part[threadIdx.x] += t;
    __syncthreads();
  }
  int run = part[threadIdx.x] - s;
#pragma unroll
  for (int i = 0; i < 4; i++) { int vv = v[i]; if (base + i < nb) bsums[base + i] = run; run += vv; }
}
__global__ void k_scanAdd(int* __restrict__ data, int n, const int* __restrict__ bsums) {
  int add = bsums[blockIdx.x];
  int base = blockIdx.x * SCTILE + threadIdx.x * 8;
#pragma unroll
  for (int i = 0; i < 8; i++) if (base + i < n) data[base + i] += add;
}

// ---------- radix sort (templated key type + digit width) ----------
template <typename K, int BITS>
__global__ void k_sortHistT(const K* __restrict__ keys, int* __restrict__ hist,
                            int shift, int nb) {
  const int RAD = 1 << BITS;
  __shared__ int h[RAD];
  for (int i = threadIdx.x; i < RAD; i += 256) h[i] = 0;
  __syncthreads();
  int base = blockIdx.x * STILE;
  for (int i = threadIdx.x; i < STILE; i += 256) {
    int d = (int)((keys[base + i] >> shift) & (RAD - 1));
    atomicAdd(&h[d], 1);
  }
  __syncthreads();
  for (int i = threadIdx.x; i < RAD; i += 256) hist[i * nb + blockIdx.x] = h[i];
}

template <typename K, int BITS>
__global__ void k_sortScatterT(const K* __restrict__ in, K* __restrict__ out,
                               const int* __restrict__ histScanned, int shift, int nb) {
  const int RAD = 1 << BITS;
  __shared__ int run[RAD];
  for (int i = threadIdx.x; i < RAD; i += 256) run[i] = 0;
  __syncthreads();
  int lane = threadIdx.x & 63;
  int wid = threadIdx.x >> 6;
  int base = blockIdx.x * STILE;
  for (int chunk = 0; chunk < 8; chunk++) {
    K key = in[base + chunk * 256 + threadIdx.x];
    int d = (int)((key >> shift) & (RAD - 1));
    u64 m = ~0ULL;
#pragma unroll
    for (int b = 0; b < BITS; b++) {
      u64 bal = __ballot((d >> b) & 1);
      m &= ((d >> b) & 1) ? bal : ~bal;
    }
    int laneRank = __popcll(m & ((1ULL << lane) - 1ULL));
    int cntm = __popcll(m);
    bool leader = (laneRank == 0);
    int local = 0;
    for (int w = 0; w < 4; w++) {
      if (wid == w) {
        int basev = run[d];
        local = basev + laneRank;
        if (leader) run[d] = basev + cntm;
      }
      __syncthreads();
    }
    out[histScanned[d * nb + blockIdx.x] + local] = key;
  }
}

// ---------- CSR of selected edges per node ----------
__global__ void k_csr(const int* __restrict__ selSrc, const int* __restrict__ selDst,
                      const int* __restrict__ selCount, const int* __restrict__ nodeOff,
                      int* __restrict__ fill, int* __restrict__ edgeIdx) {
  int n = selCount[0]; if (n > CAP) n = CAP;
  for (int e = blockIdx.x * 256 + threadIdx.x; e < n; e += gridDim.x * 256) {
    int s = selSrc[e];
    int p = atomicAdd(&fill[s], 1);
    edgeIdx[nodeOff[s] + p] = e;
    int d = selDst[e];
    int p2 = atomicAdd(&fill[d], 1);
    edgeIdx[nodeOff[d] + p2] = e;
  }
}

// ---------- cluster sum: gather per node, run-flush per cluster ----------
// cnt==0 members skipped (singleton clusters handled exactly by k_copyUntouched).
__global__ void __launch_bounds__(128) k_clusterSum(
    const u64* __restrict__ mk, const int* __restrict__ nodeOff, const int* __restrict__ cnt,
    const int* __restrict__ edgeIdx, const int* __restrict__ selSrc,
    const int* __restrict__ selDst, const float* __restrict__ selW,
    const float* __restrict__ x, int* __restrict__ accX) {
  int c = threadIdx.x;               // channel 0..127
  int base = blockIdx.x * MCHUNK;
  if (base >= NN) return;
  int end = base + MCHUNK; if (end > NN) end = NN;
  u64 k0 = mk[base];
  int clN = (int)(k0 >> 32);
  int nodeN = (int)(k0 & 0xFFFFFFFFULL);
  int cntN = cnt[nodeN];
  int offN = nodeOff[nodeN];
  int curCl = -1; int acc = 0;
  for (int m = base; m < end; m++) {
    int cl = clN, ci = cntN, o = offN;
    if (m + 1 < end) {
      u64 k1 = mk[m + 1];
      clN = (int)(k1 >> 32);
      nodeN = (int)(k1 & 0xFFFFFFFFULL);
      cntN = cnt[nodeN];
      offN = nodeOff[nodeN];
    }
    if (ci == 0) continue;           // singleton: exact copy path elsewhere
    if (cl != curCl) {
      if (curCl >= 0 && acc != 0) atomicAdd(&accX[(size_t)curCl * CF + c], acc);
      curCl = cl; acc = 0;
    }
    int eN = edgeIdx[o];
    for (int t = 0; t < ci; t++) {
      int e = eN;
      if (t + 1 < ci) eN = edgeIdx[o + t + 1];
      float r = (x[(size_t)selSrc[e] * CF + c] + x[(size_t)selDst[e] * CF + c]) * selW[e];
      acc += __float2int_rn((r / (float)ci) * XSCALE);  // same rounding as validated kernel
    }
  }
  if (curCl >= 0 && acc != 0) atomicAdd(&accX[(size_t)curCl * CF + c], acc);
}

// ---------- finalize: int fixed -> f32 (vectorized) ----------
__global__ void k_final2(const int* __restrict__ accX, float* __restrict__ outNewX) {
  int t = (blockIdx.x * 256 + threadIdx.x) * 4;
  if (t >= NN * CF) return;
  int4 v = *(const int4*)(accX + t);
  float4 o;
  o.x = (float)v.x * XINV; o.y = (float)v.y * XINV;
  o.z = (float)v.z * XINV; o.w = (float)v.w * XINV;
  *(float4*)(outNewX + t) = o;
}

// untouched nodes (cnt==0 => singleton cluster): exact f32 copy of their x row
__global__ void k_copyUntouched(const float* __restrict__ x, const int* __restrict__ cnt,
                                const int* __restrict__ cluster, float* __restrict__ outNewX) {
  int t = blockIdx.x * 256 + threadIdx.x;
  if (t >= NN * CF) return;
  int i = t >> 7; int c = t & 127;
  if (cnt[i] == 0) outNewX[(size_t)cluster[i] * CF + c] = x[t];
}

// ---------- edge coalescing: int32-WRAPPED u32 keys (JAX x64-disabled semantics) ----------
__global__ void k_keysInit(const int* __restrict__ ei, const int* __restrict__ cluster,
                           u32* __restrict__ keys) {
  int t = blockIdx.x * 256 + threadIdx.x;
  if (t >= SORT_N) return;
  if (t < EE) {
    u32 kw = (u32)cluster[ei[t]] * 100000u + (u32)cluster[ei[EE + t]];  // int32 wraparound
    keys[t] = kw ^ 0x80000000u;   // bias: unsigned order == signed order
  } else {
    keys[t] = 0xFFFFFFFFu;        // pads sort to the tail
  }
}

__global__ void k_flags(const u32* __restrict__ keys, int* __restrict__ f) {
  int j = blockIdx.x * 256 + threadIdx.x;
  if (j >= EE) return;
  f[j] = (j == 0 || keys[j] != keys[j - 1]) ? 1 : 0;
}
__global__ void k_eiFill(float* __restrict__ outEI) {
  int t = blockIdx.x * 256 + threadIdx.x;
  if (t < 2 * EE) outEI[t] = -1.0f;
}
__global__ void k_eiScatter(const u32* __restrict__ keys, const int* __restrict__ pos,
                            float* __restrict__ outEI) {
  int j = blockIdx.x * 256 + threadIdx.x;
  if (j >= EE) return;
  bool f = (j == 0 || keys[j] != keys[j - 1]);
  if (f) {
    int k32 = (int)(keys[j] ^ 0x80000000u);  // unbias -> wrapped int32 key
    if (k32 >= 0) {                           // ref: valid = keys >= 0
      int p = pos[j];
      outEI[p] = (float)(k32 / 100000);
      outEI[EE + p] = (float)(k32 % 100000);
    }
  }
}

// ---------------------------------------------------------------------------

static inline void runScan(int* data, int n, int* bsums, hipStream_t stream) {
  int nb = (n + SCTILE - 1) / SCTILE;
  k_scanBlock<<<nb, 256, 0, stream>>>(data, data, n, bsums);
  k_scanTop<<<1, 256, 0, stream>>>(bsums, nb);
  k_scanAdd<<<nb, 256, 0, stream>>>(data, n, bsums);
}
static inline void runScanFrom(const int* src, int* dst, int n, int* bsums, hipStream_t stream) {
  int nb = (n + SCTILE - 1) / SCTILE;
  k_scanBlock<<<nb, 256, 0, stream>>>(src, dst, n, bsums);
  k_scanTop<<<1, 256, 0, stream>>>(bsums, nb);
  k_scanAdd<<<nb, 256, 0, stream>>>(dst, n, bsums);
}

extern "C" void kernel_launch(void* const* d_in, const int* in_sizes, int n_in,
                              void* d_out, int out_size, void* d_ws, size_t ws_size,
                              hipStream_t stream) {
  const float* x = (const float*)d_in[0];
  const int* ei = (const int*)d_in[1];
  // d_in[2] = batch (all zeros, unused)
  const float* W = (const float*)d_in[3];
  const float* bptr = (const float*)d_in[4];

  // ---- workspace carve-up (256B aligned) ----
  char* wp = (char*)d_ws;
  auto alloc = [&](size_t bytes) -> void* {
    void* r = (void*)wp;
    wp += (bytes + 255) & ~(size_t)255;
    return r;
  };
  // Overlay region (all dead before accX memset):
  double* ez = (double*)alloc((size_t)EE * 8);           // 6.4 MB
  u32* sortA = (u32*)alloc((size_t)SORT_N * 4);          // 3.2 MB
  u32* sortB = (u32*)alloc((size_t)SORT_N * 4);          // 3.2 MB
  int* histG = (int*)alloc((size_t)HISTG_LEN * 4);       // 3.2 MB
  int* fscan = (int*)alloc((size_t)EE * 4);              // 3.2 MB (also reused as roots)
  double* p_d = (double*)alloc((size_t)NN * 8);
  double* q_d = (double*)alloc((size_t)NN * 8);
  u64* menc = (u64*)alloc((size_t)NN * 8);               // zero region A start
  u64* sdenFx = (u64*)alloc((size_t)NN * 8);             // zero region A end
  char* zeroAEnd = wp;
  // accX (51.2MB) overlays everything above (~22MB)
  int* accX = (int*)d_ws;
  const size_t ACCX_BYTES = (size_t)NN * CF * 4;
  if (wp < (char*)d_ws + ACCX_BYTES) wp = (char*)d_ws + ACCX_BYTES;
  // Persistent:
  int* cnt = (int*)alloc((size_t)NN * 4);                // zero region B start
  int* fill = (int*)alloc((size_t)NN * 4);
  int* selCount = (int*)alloc(256);                      // zero region B end
  char* zeroBStart = (char*)cnt; char* zeroBEnd = wp;
  int* nodeOff = (int*)alloc((size_t)NN * 4);
  int* selSrc = (int*)alloc((size_t)CAP * 4);
  int* selDst = (int*)alloc((size_t)CAP * 4);
  float* selW = (float*)alloc((size_t)CAP * 4);
  int* labels = (int*)alloc((size_t)NN * 4);
  int* cluster = (int*)alloc((size_t)NN * 4);
  int* edgeIdx = (int*)alloc((size_t)CAP * 4);
  u64* mA = (u64*)alloc((size_t)MSORT_N * 8);            // member sort (persistent)
  u64* mB = (u64*)alloc((size_t)MSORT_N * 8);
  int* bsums = (int*)alloc(1024 * 4);
  Sel* st = (Sel*)alloc(256);
  u32* selHist = (u32*)alloc(512 * 4);
  float* tval = (float*)alloc(256);
  (void)ws_size; (void)n_in; (void)in_sizes;

  // ---- output regions (all written as f32) ----
  float* outNewX = (float*)d_out;                       // N*C
  float* outEI = outNewX + (size_t)NN * CF;             // 2*E
  float* outBatch = outEI + 2 * (size_t)EE;             // N (zeros via memset)
  float* outScore = outBatch + NN;                      // E

  // ---- quantile index/weights (np.quantile: virtual index) ----
  double qd = 1.0 - (double)(NN / 2) / (double)EE;      // 0.9375 exact
  double posd = qd * (double)(EE - 1);                  // 749999.0625 exact
  int k0 = (int)floor(posd);
  double fracd = posd - floor(posd);                    // 0.0625 exact
  int k1 = (fracd > 0.0) ? k0 + 1 : k0;
  float frac = (float)fracd;

  // ---- init ----
  hipMemsetAsync(outBatch, 0, (size_t)NN * 4, stream);
  hipMemsetAsync(menc, 0, (size_t)(zeroAEnd - (char*)menc), stream);
  hipMemsetAsync(zeroBStart, 0, (size_t)(zeroBEnd - zeroBStart), stream);

  // ---- scores (deterministic: f64 math + exact max + fixed-point denom) ----
  k_pq<<<(NN + 3) / 4, 256, 0, stream>>>(x, W, p_d, q_d);
  k_em<<<(EE + 255) / 256, 256, 0, stream>>>(ei, p_d, q_d, bptr, ez, menc);
  k_zs<<<(EE + 255) / 256, 256, 0, stream>>>(ei, ez, menc, sdenFx);
  k_score<<<(EE + 255) / 256, 256, 0, stream>>>(ei, ez, sdenFx, outScore);

  // ---- quantile via radix select (3 passes; top byte known = 0x3F) ----
  k_selInit<<<2, 256, 0, stream>>>(st, selHist, k0, k1);
  for (int pass = 0; pass < 3; pass++) {
    k_selHist<<<1024, 256, 0, stream>>>(outScore, st, selHist, 16 - 8 * pass);
    k_selPick<<<1, 256, 0, stream>>>(st, selHist);
  }
  k_t<<<1, 64, 0, stream>>>(st, tval, frac);

  // ---- mask -> compacted edges + endpoint counts ----
  k_compact<<<(EE + 1023) / 1024, 1024, 0, stream>>>(outScore, tval, ei, selCount,
                                                     selSrc, selDst, selW, cnt);

  // ---- connected components: lock-free union-find ----
  k_labelInit<<<(NN + 255) / 256, 256, 0, stream>>>(labels);
  k_ufUnion<<<256, 256, 0, stream>>>(selSrc, selDst, selCount, labels);
  k_ufUnion<<<256, 256, 0, stream>>>(selSrc, selDst, selCount, labels);  // belt-and-braces
  k_ufFlattenRoots<<<(NN + 255) / 256, 256, 0, stream>>>(labels, fscan);

  // ---- relabel by rank of component-min; emit member sort keys fused ----
  runScan(fscan, NN, bsums, stream);
  k_clusterMkeys<<<(MSORT_N + 255) / 256, 256, 0, stream>>>(labels, fscan, cluster, mA);

  // ---- member sort: 2 passes over cluster bits (node order stable-preserved) ----
  {
    u64* msin = mA; u64* msout = mB;
    for (int pass = 0; pass < 2; pass++) {
      int shift = 32 + MBITS * pass;
      k_sortHistT<u64, MBITS><<<NB_M, 256, 0, stream>>>(msin, histG, shift, NB_M);
      runScan(histG, MRADIX * NB_M, bsums, stream);
      k_sortScatterT<u64, MBITS><<<NB_M, 256, 0, stream>>>(msin, msout, histG, shift, NB_M);
      u64* tmp = msin; msin = msout; msout = tmp;
    }
    // result in mA (persistent)
  }
  u64* memberKeys = mA;

  // ---- coalesced cluster edges: u32 keys, 3 x 11-bit passes ----
  k_keysInit<<<SORT_N / 256, 256, 0, stream>>>(ei, cluster, sortA);
  u32* sin = sortA; u32* sout = sortB;
  for (int pass = 0; pass < 3; pass++) {
    int shift = EBITS * pass;
    k_sortHistT<u32, EBITS><<<NB_E, 256, 0, stream>>>(sin, histG, shift, NB_E);
    runScan(histG, ERADIX * NB_E, bsums, stream);
    k_sortScatterT<u32, EBITS><<<NB_E, 256, 0, stream>>>(sin, sout, histG, shift, NB_E);
    u32* tmp = sin; sin = sout; sout = tmp;
  }
  // result in sortB (== sin)
  k_flags<<<(EE + 255) / 256, 256, 0, stream>>>(sin, fscan);
  runScan(fscan, EE, bsums, stream);
  k_eiFill<<<(2 * EE + 255) / 256, 256, 0, stream>>>(outEI);
  k_eiScatter<<<(EE + 255) / 256, 256, 0, stream>>>(sin, fscan, outEI);

  // ---- node CSR (nodeOff = exclusive scan of cnt, cnt preserved) ----
  runScanFrom(cnt, nodeOff, NN, bsums, stream);
  k_csr<<<256, 256, 0, stream>>>(selSrc, selDst, selCount, nodeOff, fill, edgeIdx);

  // ---- new_x: gather per node, run-flush per cluster (overlay now safe) ----
  hipMemsetAsync(accX, 0, ACCX_BYTES, stream);
  k_clusterSum<<<(NN + MCHUNK - 1) / MCHUNK, 128, 0, stream>>>(
      memberKeys, nodeOff, cnt, edgeIdx, selSrc, selDst, selW, x, accX);
  k_final2<<<(NN * CF / 4 + 255) / 256, 256, 0, stream>>>(accX, outNewX);
  k_copyUntouched<<<(NN * CF + 255) / 256, 256, 0, stream>>>(x, cnt, cluster, outNewX);
}

// Round 11
// 686.101 us; speedup vs baseline: 1.5687x; 1.0247x over previous
//
#include <hip/hip_runtime.h>
#include <math.h>
#include <stdint.h>

typedef unsigned long long u64;
typedef unsigned int u32;

#define NN 100000
#define CF 128
#define EE 800000

#define CAP 131072             // selected-edge capacity (true count <= 50000)

// ---- edge radix sort: u32 keys, 3 passes x 11 bits (radix 2048), tile 4096 ----
#define EBITS 11
#define ERADIX 2048
#define ETILE 4096
#define NB_E 196               // 196*4096 = 802816 >= EE
#define SORT_N (NB_E * ETILE)
// ---- member radix sort: u64 keys (cluster<<32)|node, 2 passes x 12 bits, tile 2048 ----
#define MBITS 12
#define MRADIX 4096
#define MTILE 2048
#define NB_M 49                // 49*2048 = 100352 >= NN
#define MSORT_N (NB_M * MTILE)
#define HISTG_LEN 401408       // max(ERADIX*NB_E=401408, MRADIX*NB_M=200704)

#define SCTILE 2048            // scan tile: 256 threads x 8
#define MCHUNK 16              // members per block in cluster-sum

// fixed-point scales (order-independent integer accumulation => bitwise determinism)
#define ZSCALE 4503599627370496.0   // 2^52 for softmax denominator (z in (0,1])
#define XSCALE 32768.0f             // 2^15 for new_x contributions
#define XINV   (1.0f / 32768.0f)

struct Sel { u32 prefix; u32 k; };

__device__ inline u64 encD(double v) {
  u64 u = (u64)__double_as_longlong(v);
  return u ^ ((u >> 63) ? ~0ULL : 0x8000000000000000ULL);
}
__device__ inline double decD(u64 u) {
  u ^= ((u >> 63) ? 0x8000000000000000ULL : ~0ULL);
  return __longlong_as_double((long long)u);
}

// ---------- per-node dot products p = x.W[:C], q = x.W[C:], f64 ----------
__global__ void k_pq(const float* __restrict__ x, const float* __restrict__ W,
                     double* __restrict__ p, double* __restrict__ q) {
  int node = blockIdx.x * 4 + (threadIdx.x >> 6);
  int lane = threadIdx.x & 63;
  if (node >= NN) return;
  const float* xr = x + (size_t)node * CF;
  double a = (double)xr[lane] * (double)W[lane] + (double)xr[lane + 64] * (double)W[lane + 64];
  double c = (double)xr[lane] * (double)W[CF + lane] + (double)xr[lane + 64] * (double)W[CF + lane + 64];
  for (int off = 32; off; off >>= 1) { a += __shfl_xor(a, off); c += __shfl_xor(c, off); }
  if (lane == 0) { p[node] = a; q[node] = c; }
}

// ---------- e = p[src]+q[dst]+b ; segment max into menc (exact, order-free) ----------
__global__ void k_em(const int* __restrict__ ei, const double* __restrict__ p,
                     const double* __restrict__ q, const float* __restrict__ bptr,
                     double* __restrict__ e, u64* __restrict__ menc) {
  int j = blockIdx.x * 256 + threadIdx.x;
  if (j >= EE) return;
  int s = ei[j], d = ei[EE + j];
  double ev = p[s] + q[d] + (double)bptr[0];
  e[j] = ev;
  atomicMax(&menc[d], encD(ev));
}

// ---------- z = exp(e-m[dst]) (in place) ; fixed-point segment sum ----------
__global__ void k_zs(const int* __restrict__ ei, double* __restrict__ e,
                     const u64* __restrict__ menc, u64* __restrict__ sdenFx) {
  int j = blockIdx.x * 256 + threadIdx.x;
  if (j >= EE) return;
  int d = ei[EE + j];
  double z = exp(e[j] - decD(menc[d]));
  e[j] = z;
  atomicAdd(&sdenFx[d], (u64)__double2ll_rn(z * ZSCALE));
}

// ---------- score = z/s[dst] + 0.5 -> f32 out (fully deterministic) ----------
// NOTE: z/s in (0,1] => score in (0.5, 1.5] => f32 top byte is ALWAYS 0x3F.
__global__ void k_score(const int* __restrict__ ei, const double* __restrict__ z,
                        const u64* __restrict__ sdenFx, float* __restrict__ outScore) {
  int j = blockIdx.x * 256 + threadIdx.x;
  if (j >= EE) return;
  int d = ei[EE + j];
  double s = (double)sdenFx[d] * (1.0 / ZSCALE);
  outScore[j] = (float)(z[j] / s + 0.5);
}

// ---------- radix select (two order statistics; top byte pre-resolved = 0x3F) ----------
__global__ void k_selInit(Sel* st, u32* hist, int k0, int k1) {
  int t = blockIdx.x * 256 + threadIdx.x;
  if (t == 0) { st[0].prefix = 0x3Fu; st[0].k = (u32)k0; st[1].prefix = 0x3Fu; st[1].k = (u32)k1; }
  if (t < 512) hist[t] = 0;
}

__global__ void k_selHist(const float* __restrict__ score, const Sel* __restrict__ st,
                          u32* __restrict__ hist, int shift) {
  __shared__ u32 h[512];
  for (int i = threadIdx.x; i < 512; i += 256) h[i] = 0;
  __syncthreads();
  u32 p0 = st[0].prefix, p1 = st[1].prefix;
  for (int j = blockIdx.x * 256 + threadIdx.x; j < EE; j += gridDim.x * 256) {
    u32 u = __float_as_uint(score[j]);
    u32 d = (u >> shift) & 255u;
    if ((u >> (shift + 8)) == p0) atomicAdd(&h[d], 1u);
    if ((u >> (shift + 8)) == p1) atomicAdd(&h[256 + d], 1u);
  }
  __syncthreads();
  for (int i = threadIdx.x; i < 512; i += 256) if (h[i]) atomicAdd(&hist[i], h[i]);
}

// last==1: also emit threshold t = a + (b-a)*frac (numpy _lerp; t in [a,b))
__global__ void k_selPick(Sel* st, u32* hist, float* tval, float frac, int last) {
  if (threadIdx.x == 0) {
    for (int sel = 0; sel < 2; sel++) {
      u32 k = st[sel].k, cum = 0;
      for (int b = 0; b < 256; b++) {
        u32 c = hist[sel * 256 + b];
        if (cum + c > k) { st[sel].prefix = (st[sel].prefix << 8) | (u32)b; st[sel].k = k - cum; break; }
        cum += c;
      }
    }
    if (last) {
      float a = __uint_as_float(st[0].prefix);
      float b = __uint_as_float(st[1].prefix);
      tval[0] = __fadd_rn(a, __fmul_rn(__fsub_rn(b, a), frac));
    }
  }
  __syncthreads();
  for (int i = threadIdx.x; i < 512; i += blockDim.x) hist[i] = 0;
}

// ---------- mask -> compacted edge list + endpoint counts (+ fused label init) ----------
__global__ void __launch_bounds__(1024) k_compact(
    const float* __restrict__ score, const float* __restrict__ tval,
    const int* __restrict__ ei, int* __restrict__ selCount,
    int* __restrict__ selSrc, int* __restrict__ selDst,
    float* __restrict__ selW, int* __restrict__ cnt, int* __restrict__ labels) {
  __shared__ int wbase[16];
  int j = blockIdx.x * 1024 + threadIdx.x;
  if (j < NN) labels[j] = j;            // fused union-find init
  int lane = threadIdx.x & 63;
  int wid = threadIdx.x >> 6;
  float sc = 0.0f;
  bool sel = false;
  if (j < EE) { sc = score[j]; sel = (sc > tval[0]); }
  u64 m = __ballot(sel);
  int wcnt = __popcll(m);
  int rank = __popcll(m & ((1ULL << lane) - 1ULL));
  if (lane == 0) wbase[wid] = wcnt;
  __syncthreads();
  if (threadIdx.x == 0) {
    int tot = 0;
#pragma unroll
    for (int w = 0; w < 16; w++) tot += wbase[w];
    int base = tot ? atomicAdd(selCount, tot) : 0;
#pragma unroll
    for (int w = 0; w < 16; w++) { int c = wbase[w]; wbase[w] = base; base += c; }
  }
  __syncthreads();
  if (sel) {
    int s = ei[j], d = ei[EE + j];
    int pos = wbase[wid] + rank;
    if (pos < CAP) { selSrc[pos] = s; selDst[pos] = d; selW[pos] = sc; }
    atomicAdd(&cnt[s], 1);
    atomicAdd(&cnt[d], 1);
  }
}

// ---------- connected components: lock-free union-find (validated r7-r10) ----------
__device__ inline int uf_find(int* parent, int x) {
  while (true) {
    int p = parent[x];
    if (p == x) return x;
    int gp = parent[p];
    if (gp == p) return p;
    parent[x] = gp;           // path halving (benign race)
    x = gp;
  }
}

__global__ void k_ufUnion(const int* __restrict__ selSrc, const int* __restrict__ selDst,
                          const int* __restrict__ selCount, int* __restrict__ parent) {
  int n = selCount[0]; if (n > CAP) n = CAP;
  for (int e = blockIdx.x * 256 + threadIdx.x; e < n; e += gridDim.x * 256) {
    int ru = uf_find(parent, selSrc[e]);
    int rv = uf_find(parent, selDst[e]);
    while (ru != rv) {
      if (ru < rv) { int t = ru; ru = rv; rv = t; }
      int old = atomicCAS(&parent[ru], ru, rv);
      if (old == ru) break;
      ru = uf_find(parent, old);
      rv = uf_find(parent, rv);
    }
  }
}

// flatten + emit root flags (fused)
__global__ void k_ufFlattenRoots(int* __restrict__ parent, int* __restrict__ roots) {
  int i = blockIdx.x * 256 + threadIdx.x;
  if (i >= NN) return;
  int x = i;
  while (true) { int p = parent[x]; if (p == x) break; x = p; }
  parent[i] = x;
  roots[i] = (x == i) ? 1 : 0;
}

// cluster id + member sort key + rootNode map (fused)
__global__ void k_clusterMkeys(const int* __restrict__ labels, const int* __restrict__ rootScan,
                               int* __restrict__ cluster, u64* __restrict__ mkeys,
                               int* __restrict__ rootNode) {
  int i = blockIdx.x * 256 + threadIdx.x;
  if (i < NN) {
    int cl = rootScan[labels[i]];
    cluster[i] = cl;
    mkeys[i] = ((u64)(u32)cl << 32) | (u32)i;
    if (labels[i] == i) rootNode[cl] = i;
  } else if (i < MSORT_N) {
    mkeys[i] = ~0ULL;
  }
}

// ---------- generic exclusive scan (3-launch, validated) ----------
__global__ void k_scanBlock(const int* __restrict__ src, int* __restrict__ dst,
                            int n, int* __restrict__ bsums) {
  __shared__ int part[256];
  int base = blockIdx.x * SCTILE + threadIdx.x * 8;
  int v[8]; int s = 0;
#pragma unroll
  for (int i = 0; i < 8; i++) { v[i] = (base + i < n) ? src[base + i] : 0; s += v[i]; }
  part[threadIdx.x] = s;
  __syncthreads();
  for (int off = 1; off < 256; off <<= 1) {
    int t = (threadIdx.x >= off) ? part[threadIdx.x - off] : 0;
    __syncthreads();
    part[threadIdx.x] += t;
    __syncthreads();
  }
  int run = part[threadIdx.x] - s;
#pragma unroll
  for (int i = 0; i < 8; i++) { int vv = v[i]; if (base + i < n) dst[base + i] = run; run += vv; }
  if (threadIdx.x == 255) bsums[blockIdx.x] = part[255];
}
// flag-scan fusion: flags computed inline from sorted keys (saves a kernel + 6.4MB)
__global__ void k_scanFlags(const u32* __restrict__ keys, int* __restrict__ dst,
                            int n, int* __restrict__ bsums) {
  __shared__ int part[256];
  int base = blockIdx.x * SCTILE + threadIdx.x * 8;
  int v[8]; int s = 0;
#pragma unroll
  for (int i = 0; i < 8; i++) {
    int j = base + i;
    v[i] = (j < n) ? ((j == 0 || keys[j] != keys[j - 1]) ? 1 : 0) : 0;
    s += v[i];
  }
  part[threadIdx.x] = s;
  __syncthreads();
  for (int off = 1; off < 256; off <<= 1) {
    int t = (threadIdx.x >= off) ? part[threadIdx.x - off] : 0;
    __syncthreads();
    part[threadIdx.x] += t;
    __syncthreads();
  }
  int run = part[threadIdx.x] - s;
#pragma unroll
  for (int i = 0; i < 8; i++) { int vv = v[i]; if (base + i < n) dst[base + i] = run; run += vv; }
  if (threadIdx.x == 255) bsums[blockIdx.x] = part[255];
}
__global__ void k_scanTop(int* __restrict__ bsums, int nb) {
  __shared__ int part[256];
  int base = threadIdx.x * 4;
  int v[4]; int s = 0;
#pragma unroll
  for (int i = 0; i < 4; i++) { v[i] = (base + i < nb) ? bsums[base + i] : 0; s += v[i]; }
  part[threadIdx.x] = s;
  __syncthreads();
  for (int off = 1; off < 256; off <<= 1) {
    int t = (threadIdx.x >= off) ? part[threadIdx.x - off] : 0;
    __syncthreads();
    part[threadIdx.x] += t;
    __syncthreads();
  }
  int run = part[threadIdx.x] - s;
#pragma unroll
  for (int i = 0; i < 4; i++) { int vv = v[i]; if (base + i < nb) bsums[base + i] = run; run += vv; }
}
__global__ void k_scanAdd(int* __restrict__ data, int n, const int* __restrict__ bsums) {
  int add = bsums[blockIdx.x];
  int base = blockIdx.x * SCTILE + threadIdx.x * 8;
#pragma unroll
  for (int i = 0; i < 8; i++) if (base + i < n) data[base + i] += add;
}

// ---------- radix sort (templated key type + digit width + tile) ----------
template <typename K, int BITS, int TILE>
__global__ void k_sortHistT(const K* __restrict__ keys, int* __restrict__ hist,
                            int shift, int nb) {
  const int RAD = 1 << BITS;
  __shared__ int h[RAD];
  for (int i = threadIdx.x; i < RAD; i += 256) h[i] = 0;
  __syncthreads();
  int base = blockIdx.x * TILE;
  for (int i = threadIdx.x; i < TILE; i += 256) {
    int d = (int)((keys[base + i] >> shift) & (RAD - 1));
    atomicAdd(&h[d], 1);
  }
  __syncthreads();
  for (int i = threadIdx.x; i < RAD; i += 256) hist[i * nb + blockIdx.x] = h[i];
}

template <typename K, int BITS, int TILE>
__global__ void k_sortScatterT(const K* __restrict__ in, K* __restrict__ out,
                               const int* __restrict__ histScanned, int shift, int nb) {
  const int RAD = 1 << BITS;
  const int CH = TILE / 256;
  __shared__ int run[RAD];
  for (int i = threadIdx.x; i < RAD; i += 256) run[i] = 0;
  __syncthreads();
  int lane = threadIdx.x & 63;
  int wid = threadIdx.x >> 6;
  int base = blockIdx.x * TILE;
  for (int chunk = 0; chunk < CH; chunk++) {
    K key = in[base + chunk * 256 + threadIdx.x];
    int d = (int)((key >> shift) & (RAD - 1));
    u64 m = ~0ULL;
#pragma unroll
    for (int b = 0; b < BITS; b++) {
      u64 bal = __ballot((d >> b) & 1);
      m &= ((d >> b) & 1) ? bal : ~bal;
    }
    int laneRank = __popcll(m & ((1ULL << lane) - 1ULL));
    int cntm = __popcll(m);
    bool leader = (laneRank == 0);
    int local = 0;
    for (int w = 0; w < 4; w++) {
      if (wid == w) {
        int basev = run[d];
        local = basev + laneRank;
        if (leader) run[d] = basev + cntm;
      }
      __syncthreads();
    }
    out[histScanned[d * nb + blockIdx.x] + local] = key;
  }
}

// ---------- CSR of selected edges per node ----------
__global__ void k_csr(const int* __restrict__ selSrc, const int* __restrict__ selDst,
                      const int* __restrict__ selCount, const int* __restrict__ nodeOff,
                      int* __restrict__ fill, int* __restrict__ edgeIdx) {
  int n = selCount[0]; if (n > CAP) n = CAP;
  for (int e = blockIdx.x * 256 + threadIdx.x; e < n; e += gridDim.x * 256) {
    int s = selSrc[e];
    int p = atomicAdd(&fill[s], 1);
    edgeIdx[nodeOff[s] + p] = e;
    int d = selDst[e];
    int p2 = atomicAdd(&fill[d], 1);
    edgeIdx[nodeOff[d] + p2] = e;
  }
}

// ---------- cluster sum: gather per node, run-flush per cluster, 2-level prefetch ----------
__global__ void __launch_bounds__(128) k_clusterSum(
    const u64* __restrict__ mk, const int* __restrict__ nodeOff, const int* __restrict__ cnt,
    const int* __restrict__ edgeIdx, const int* __restrict__ selSrc,
    const int* __restrict__ selDst, const float* __restrict__ selW,
    const float* __restrict__ x, int* __restrict__ accX) {
  int c = threadIdx.x;               // channel 0..127
  int base = blockIdx.x * MCHUNK;
  if (base >= NN) return;
  int end = base + MCHUNK; if (end > NN) end = NN;
  u64 k0 = mk[base];
  int clN = (int)(k0 >> 32);
  int nodeN = (int)(k0 & 0xFFFFFFFFULL);
  int cntN = cnt[nodeN];
  int offN = nodeOff[nodeN];
  int curCl = -1; int acc = 0;
  for (int m = base; m < end; m++) {
    int cl = clN, ci = cntN, o = offN;
    if (m + 1 < end) {                 // member-level prefetch
      u64 k1 = mk[m + 1];
      clN = (int)(k1 >> 32);
      nodeN = (int)(k1 & 0xFFFFFFFFULL);
      cntN = cnt[nodeN];
      offN = nodeOff[nodeN];
    }
    if (ci == 0) continue;             // singleton: exact copy path in k_finalFused
    if (cl != curCl) {
      if (curCl >= 0 && acc != 0) atomicAdd(&accX[(size_t)curCl * CF + c], acc);
      curCl = cl; acc = 0;
    }
    // edge-level pipeline: prefetch next edge's rows while computing current
    int e0 = edgeIdx[o];
    float w = selW[e0];
    float xs = x[(size_t)selSrc[e0] * CF + c];
    float xd = x[(size_t)selDst[e0] * CF + c];
    for (int t = 0; t < ci; t++) {
      float cur = (xs + xd) * w;
      if (t + 1 < ci) {
        int e1 = edgeIdx[o + t + 1];
        w = selW[e1];
        xs = x[(size_t)selSrc[e1] * CF + c];
        xd = x[(size_t)selDst[e1] * CF + c];
      }
      acc += __float2int_rn((cur / (float)ci) * XSCALE);  // same rounding as validated
    }
  }
  if (curCl >= 0 && acc != 0) atomicAdd(&accX[(size_t)curCl * CF + c], acc);
}

// ---------- fused finalize: accX -> f32, singleton rows exact-copied, padding zeroed ----------
__global__ void k_finalFused(const float* __restrict__ x, const int* __restrict__ cnt,
                             const int* __restrict__ rootNode, const int* __restrict__ accX,
                             float* __restrict__ outNewX) {
  int t = (blockIdx.x * 256 + threadIdx.x) * 4;
  if (t >= NN * CF) return;
  int cl = t >> 7; int c = t & 127;   // 4 consecutive channels, same row
  int r = rootNode[cl];               // -1 for padding rows (0xFF memset)
  float4 o;
  if (r < 0) {
    o.x = o.y = o.z = o.w = 0.0f;
  } else if (cnt[r] == 0) {
    const float* xr = x + (size_t)r * CF + c;
    o.x = xr[0]; o.y = xr[1]; o.z = xr[2]; o.w = xr[3];
  } else {
    int4 v = *(const int4*)(accX + t);
    o.x = (float)v.x * XINV; o.y = (float)v.y * XINV;
    o.z = (float)v.z * XINV; o.w = (float)v.w * XINV;
  }
  *(float4*)(outNewX + t) = o;
}

// ---------- edge coalescing: int32-WRAPPED u32 keys (JAX x64-disabled semantics) ----------
__global__ void k_keysInit(const int* __restrict__ ei, const int* __restrict__ cluster,
                           u32* __restrict__ keys) {
  int t = blockIdx.x * 256 + threadIdx.x;
  if (t >= SORT_N) return;
  if (t < EE) {
    u32 kw = (u32)cluster[ei[t]] * 100000u + (u32)cluster[ei[EE + t]];  // int32 wraparound
    keys[t] = kw ^ 0x80000000u;   // bias: unsigned order == signed order
  } else {
    keys[t] = 0xFFFFFFFFu;        // pads sort to the tail
  }
}

__global__ void k_eiFill(float* __restrict__ outEI) {
  int t = blockIdx.x * 256 + threadIdx.x;
  if (t < 2 * EE) outEI[t] = -1.0f;
}
__global__ void k_eiScatter(const u32* __restrict__ keys, const int* __restrict__ pos,
                            float* __restrict__ outEI) {
  int j = blockIdx.x * 256 + threadIdx.x;
  if (j >= EE) return;
  bool f = (j == 0 || keys[j] != keys[j - 1]);
  if (f) {
    int k32 = (int)(keys[j] ^ 0x80000000u);  // unbias -> wrapped int32 key
    if (k32 >= 0) {                           // ref: valid = keys >= 0
      int p = pos[j];
      outEI[p] = (float)(k32 / 100000);
      outEI[EE + p] = (float)(k32 % 100000);
    }
  }
}

// ---------------------------------------------------------------------------

static inline void runScan(int* data, int n, int* bsums, hipStream_t stream) {
  int nb = (n + SCTILE - 1) / SCTILE;
  k_scanBlock<<<nb, 256, 0, stream>>>(data, data, n, bsums);
  k_scanTop<<<1, 256, 0, stream>>>(bsums, nb);
  k_scanAdd<<<nb, 256, 0, stream>>>(data, n, bsums);
}
static inline void runScanFrom(const int* src, int* dst, int n, int* bsums, hipStream_t stream) {
  int nb = (n + SCTILE - 1) / SCTILE;
  k_scanBlock<<<nb, 256, 0, stream>>>(src, dst, n, bsums);
  k_scanTop<<<1, 256, 0, stream>>>(bsums, nb);
  k_scanAdd<<<nb, 256, 0, stream>>>(dst, n, bsums);
}

extern "C" void kernel_launch(void* const* d_in, const int* in_sizes, int n_in,
                              void* d_out, int out_size, void* d_ws, size_t ws_size,
                              hipStream_t stream) {
  const float* x = (const float*)d_in[0];
  const int* ei = (const int*)d_in[1];
  // d_in[2] = batch (all zeros, unused)
  const float* W = (const float*)d_in[3];
  const float* bptr = (const float*)d_in[4];

  // ---- workspace carve-up (256B aligned) ----
  char* wp = (char*)d_ws;
  auto alloc = [&](size_t bytes) -> void* {
    void* r = (void*)wp;
    wp += (bytes + 255) & ~(size_t)255;
    return r;
  };
  // Overlay region (all dead before accX memset):
  double* ez = (double*)alloc((size_t)EE * 8);           // 6.4 MB
  u32* sortA = (u32*)alloc((size_t)SORT_N * 4);          // 3.2 MB
  u32* sortB = (u32*)alloc((size_t)SORT_N * 4);          // 3.2 MB
  int* histG = (int*)alloc((size_t)HISTG_LEN * 4);       // 1.6 MB
  int* fscan = (int*)alloc((size_t)EE * 4);              // 3.2 MB (also reused as roots)
  double* p_d = (double*)alloc((size_t)NN * 8);
  double* q_d = (double*)alloc((size_t)NN * 8);
  u64* menc = (u64*)alloc((size_t)NN * 8);               // zero region A start
  u64* sdenFx = (u64*)alloc((size_t)NN * 8);             // zero region A end
  char* zeroAEnd = wp;
  // accX (51.2MB) overlays everything above (~20MB)
  int* accX = (int*)d_ws;
  const size_t ACCX_BYTES = (size_t)NN * CF * 4;
  if (wp < (char*)d_ws + ACCX_BYTES) wp = (char*)d_ws + ACCX_BYTES;
  // Persistent:
  int* cnt = (int*)alloc((size_t)NN * 4);                // zero region B start
  int* fill = (int*)alloc((size_t)NN * 4);
  int* selCount = (int*)alloc(256);                      // zero region B end
  char* zeroBStart = (char*)cnt; char* zeroBEnd = wp;
  int* rootNode = (int*)alloc((size_t)NN * 4);           // 0xFF memset (-1)
  int* nodeOff = (int*)alloc((size_t)NN * 4);
  int* selSrc = (int*)alloc((size_t)CAP * 4);
  int* selDst = (int*)alloc((size_t)CAP * 4);
  float* selW = (float*)alloc((size_t)CAP * 4);
  int* labels = (int*)alloc((size_t)NN * 4);
  int* cluster = (int*)alloc((size_t)NN * 4);
  int* edgeIdx = (int*)alloc((size_t)CAP * 4);
  u64* mA = (u64*)alloc((size_t)MSORT_N * 8);            // member sort (persistent)
  u64* mB = (u64*)alloc((size_t)MSORT_N * 8);
  int* bsums = (int*)alloc(1024 * 4);
  Sel* st = (Sel*)alloc(256);
  u32* selHist = (u32*)alloc(512 * 4);
  float* tval = (float*)alloc(256);
  (void)ws_size; (void)n_in; (void)in_sizes;

  // ---- output regions (all written as f32) ----
  float* outNewX = (float*)d_out;                       // N*C
  float* outEI = outNewX + (size_t)NN * CF;             // 2*E
  float* outBatch = outEI + 2 * (size_t)EE;             // N (zeros via memset)
  float* outScore = outBatch + NN;                      // E

  // ---- quantile index/weights (np.quantile: virtual index) ----
  double qd = 1.0 - (double)(NN / 2) / (double)EE;      // 0.9375 exact
  double posd = qd * (double)(EE - 1);                  // 749999.0625 exact
  int k0 = (int)floor(posd);
  double fracd = posd - floor(posd);                    // 0.0625 exact
  int k1 = (fracd > 0.0) ? k0 + 1 : k0;
  float frac = (float)fracd;

  // ---- init ----
  hipMemsetAsync(outBatch, 0, (size_t)NN * 4, stream);
  hipMemsetAsync(menc, 0, (size_t)(zeroAEnd - (char*)menc), stream);
  hipMemsetAsync(zeroBStart, 0, (size_t)(zeroBEnd - zeroBStart), stream);
  hipMemsetAsync(rootNode, 0xFF, (size_t)NN * 4, stream);   // -1 sentinel

  // ---- scores (deterministic: f64 math + exact max + fixed-point denom) ----
  k_pq<<<(NN + 3) / 4, 256, 0, stream>>>(x, W, p_d, q_d);
  k_em<<<(EE + 255) / 256, 256, 0, stream>>>(ei, p_d, q_d, bptr, ez, menc);
  k_zs<<<(EE + 255) / 256, 256, 0, stream>>>(ei, ez, menc, sdenFx);
  k_score<<<(EE + 255) / 256, 256, 0, stream>>>(ei, ez, sdenFx, outScore);

  // ---- quantile via radix select (3 passes; top byte known = 0x3F) ----
  k_selInit<<<2, 256, 0, stream>>>(st, selHist, k0, k1);
  for (int pass = 0; pass < 3; pass++) {
    k_selHist<<<1024, 256, 0, stream>>>(outScore, st, selHist, 16 - 8 * pass);
    k_selPick<<<1, 256, 0, stream>>>(st, selHist, tval, frac, pass == 2);
  }

  // ---- mask -> compacted edges + endpoint counts (+ label init) ----
  k_compact<<<(EE + 1023) / 1024, 1024, 0, stream>>>(outScore, tval, ei, selCount,
                                                     selSrc, selDst, selW, cnt, labels);

  // ---- connected components: lock-free union-find ----
  k_ufUnion<<<256, 256, 0, stream>>>(selSrc, selDst, selCount, labels);
  k_ufUnion<<<256, 256, 0, stream>>>(selSrc, selDst, selCount, labels);  // belt-and-braces
  k_ufFlattenRoots<<<(NN + 255) / 256, 256, 0, stream>>>(labels, fscan);

  // ---- relabel by rank of component-min; emit member keys + rootNode fused ----
  runScan(fscan, NN, bsums, stream);
  k_clusterMkeys<<<(MSORT_N + 255) / 256, 256, 0, stream>>>(labels, fscan, cluster, mA, rootNode);

  // ---- member sort: 2 passes over cluster bits (node order stable-preserved) ----
  {
    u64* msin = mA; u64* msout = mB;
    for (int pass = 0; pass < 2; pass++) {
      int shift = 32 + MBITS * pass;
      k_sortHistT<u64, MBITS, MTILE><<<NB_M, 256, 0, stream>>>(msin, histG, shift, NB_M);
      runScan(histG, MRADIX * NB_M, bsums, stream);
      k_sortScatterT<u64, MBITS, MTILE><<<NB_M, 256, 0, stream>>>(msin, msout, histG, shift, NB_M);
      u64* tmp = msin; msin = msout; msout = tmp;
    }
    // result in mA (persistent)
  }
  u64* memberKeys = mA;

  // ---- coalesced cluster edges: u32 keys, 3 x 11-bit passes, tile 4096 ----
  k_keysInit<<<SORT_N / 256, 256, 0, stream>>>(ei, cluster, sortA);
  u32* sin = sortA; u32* sout = sortB;
  for (int pass = 0; pass < 3; pass++) {
    int shift = EBITS * pass;
    k_sortHistT<u32, EBITS, ETILE><<<NB_E, 256, 0, stream>>>(sin, histG, shift, NB_E);
    runScan(histG, ERADIX * NB_E, bsums, stream);
    k_sortScatterT<u32, EBITS, ETILE><<<NB_E, 256, 0, stream>>>(sin, sout, histG, shift, NB_E);
    u32* tmp = sin; sin = sout; sout = tmp;
  }
  // result in sortB (== sin)
  {
    int nb = (EE + SCTILE - 1) / SCTILE;
    k_scanFlags<<<nb, 256, 0, stream>>>(sin, fscan, EE, bsums);
    k_scanTop<<<1, 256, 0, stream>>>(bsums, nb);
    k_scanAdd<<<nb, 256, 0, stream>>>(fscan, EE, bsums);
  }
  k_eiFill<<<(2 * EE + 255) / 256, 256, 0, stream>>>(outEI);
  k_eiScatter<<<(EE + 255) / 256, 256, 0, stream>>>(sin, fscan, outEI);

  // ---- node CSR (nodeOff = exclusive scan of cnt, cnt preserved) ----
  runScanFrom(cnt, nodeOff, NN, bsums, stream);
  k_csr<<<256, 256, 0, stream>>>(selSrc, selDst, selCount, nodeOff, fill, edgeIdx);

  // ---- new_x: gather per node, run-flush per cluster (overlay now safe) ----
  hipMemsetAsync(accX, 0, ACCX_BYTES, stream);
  k_clusterSum<<<(NN + MCHUNK - 1) / MCHUNK, 128, 0, stream>>>(
      memberKeys, nodeOff, cnt, edgeIdx, selSrc, selDst, selW, x, accX);
  k_finalFused<<<(NN * CF / 4 + 255) / 256, 256, 0, stream>>>(x, cnt, rootNode, accX, outNewX);
}

// Round 12
// 596.055 us; speedup vs baseline: 1.8057x; 1.1511x over previous
//
#include <hip/hip_runtime.h>
#include <math.h>
#include <stdint.h>

typedef unsigned long long u64;
typedef unsigned int u32;

#define NN 100000
#define CF 128
#define EE 800000

#define CAP 131072             // selected-edge capacity (true count == 50000)

// ---- edge radix sort: u32 keys, 3 passes x 11 bits (radix 2048), tile 4096 ----
#define EBITS 11
#define ERADIX 2048
#define ETILE 4096
#define NB_E 196               // 196*4096 = 802816 >= EE
#define SORT_N (NB_E * ETILE)
// ---- selected-edge key sort: u64 (cluster<<16)|e, 2 passes x 12 bits over cluster ----
#define KBITS 12
#define KRADIX 4096
#define KTILE 2048
#define NB_EK 32               // 32*2048 = 65536 >= selCount (==50000)
#define EK_N (NB_EK * KTILE)
#define HISTG_LEN 401408       // max(ERADIX*NB_E=401408, KRADIX*NB_EK=131072)

#define SCTILE 2048            // scan tile: 256 threads x 8
#define ECHUNK 16              // edges per block in cluster-sum

// fixed-point scales (order-independent integer accumulation => bitwise determinism)
#define ZSCALE 4503599627370496.0   // 2^52 for softmax denominator (z in (0,1])
#define XSCALE 32768.0f             // 2^15 for new_x contributions
#define XINV   (1.0f / 32768.0f)

struct Sel { u32 prefix; u32 k; };

__device__ inline u64 encD(double v) {
  u64 u = (u64)__double_as_longlong(v);
  return u ^ ((u >> 63) ? ~0ULL : 0x8000000000000000ULL);
}
__device__ inline double decD(u64 u) {
  u ^= ((u >> 63) ? 0x8000000000000000ULL : ~0ULL);
  return __longlong_as_double((long long)u);
}

// ---------- per-node dot products p = x.W[:C], q = x.W[C:], f64 ----------
__global__ void k_pq(const float* __restrict__ x, const float* __restrict__ W,
                     double* __restrict__ p, double* __restrict__ q) {
  int node = blockIdx.x * 4 + (threadIdx.x >> 6);
  int lane = threadIdx.x & 63;
  if (node >= NN) return;
  const float* xr = x + (size_t)node * CF;
  double a = (double)xr[lane] * (double)W[lane] + (double)xr[lane + 64] * (double)W[lane + 64];
  double c = (double)xr[lane] * (double)W[CF + lane] + (double)xr[lane + 64] * (double)W[CF + lane + 64];
  for (int off = 32; off; off >>= 1) { a += __shfl_xor(a, off); c += __shfl_xor(c, off); }
  if (lane == 0) { p[node] = a; q[node] = c; }
}

// ---------- e = p[src]+q[dst]+b ; segment max into menc (exact, order-free) ----------
__global__ void k_em(const int* __restrict__ ei, const double* __restrict__ p,
                     const double* __restrict__ q, const float* __restrict__ bptr,
                     double* __restrict__ e, u64* __restrict__ menc) {
  int j = blockIdx.x * 256 + threadIdx.x;
  if (j >= EE) return;
  int s = ei[j], d = ei[EE + j];
  double ev = p[s] + q[d] + (double)bptr[0];
  e[j] = ev;
  atomicMax(&menc[d], encD(ev));
}

// ---------- z = exp(e-m[dst]) (in place) ; fixed-point segment sum ----------
__global__ void k_zs(const int* __restrict__ ei, double* __restrict__ e,
                     const u64* __restrict__ menc, u64* __restrict__ sdenFx) {
  int j = blockIdx.x * 256 + threadIdx.x;
  if (j >= EE) return;
  int d = ei[EE + j];
  double z = exp(e[j] - decD(menc[d]));
  e[j] = z;
  atomicAdd(&sdenFx[d], (u64)__double2ll_rn(z * ZSCALE));
}

// ---------- score = z/s[dst] + 0.5 -> f32 out (fully deterministic) ----------
// score in (0.5, 1.5] => f32 top byte is ALWAYS 0x3F.
__global__ void k_score(const int* __restrict__ ei, const double* __restrict__ z,
                        const u64* __restrict__ sdenFx, float* __restrict__ outScore) {
  int j = blockIdx.x * 256 + threadIdx.x;
  if (j >= EE) return;
  int d = ei[EE + j];
  double s = (double)sdenFx[d] * (1.0 / ZSCALE);
  outScore[j] = (float)(z[j] / s + 0.5);
}

// ---------- radix select: 2 passes x 12 bits (top byte pre-resolved = 0x3F) ----------
__global__ void k_selInit(Sel* st, u32* hist, int k0, int k1) {
  int t = blockIdx.x * 256 + threadIdx.x;
  if (t == 0) { st[0].prefix = 0x3Fu; st[0].k = (u32)k0; st[1].prefix = 0x3Fu; st[1].k = (u32)k1; }
  if (t < 2 * KRADIX) hist[t] = 0;
}

__global__ void k_selHist12(const float* __restrict__ score, const Sel* __restrict__ st,
                            u32* __restrict__ hist, int shift) {
  __shared__ u32 h[2 * KRADIX];
  for (int i = threadIdx.x; i < 2 * KRADIX; i += 256) h[i] = 0;
  __syncthreads();
  u32 p0 = st[0].prefix, p1 = st[1].prefix;
  for (int j = blockIdx.x * 256 + threadIdx.x; j < EE; j += gridDim.x * 256) {
    u32 u = __float_as_uint(score[j]);
    u32 d = (u >> shift) & (KRADIX - 1);
    if ((u >> (shift + 12)) == p0) atomicAdd(&h[d], 1u);
    if ((u >> (shift + 12)) == p1) atomicAdd(&h[KRADIX + d], 1u);
  }
  __syncthreads();
  for (int i = threadIdx.x; i < 2 * KRADIX; i += 256) if (h[i]) atomicAdd(&hist[i], h[i]);
}

// parallel 4096-bin pick; last==1 also emits threshold (numpy _lerp, t in [a,b))
__global__ void k_selPick12(Sel* st, u32* hist, float* tval, float frac, int last) {
  __shared__ u32 part[256];
  for (int sel = 0; sel < 2; sel++) {
    u32 k = st[sel].k;
    u32 loc[16]; u32 s = 0;
    int base = sel * KRADIX + threadIdx.x * 16;
#pragma unroll
    for (int i = 0; i < 16; i++) { loc[i] = hist[base + i]; s += loc[i]; }
    part[threadIdx.x] = s;
    __syncthreads();
    for (int off = 1; off < 256; off <<= 1) {
      u32 t = (threadIdx.x >= off) ? part[threadIdx.x - off] : 0;
      __syncthreads();
      part[threadIdx.x] += t;
      __syncthreads();
    }
    u32 excl = part[threadIdx.x] - s;
    if (k >= excl && k < excl + s) {      // exactly one thread matches
      u32 cum = excl;
#pragma unroll
      for (int i = 0; i < 16; i++) {
        if (cum + loc[i] > k) {
          st[sel].prefix = (st[sel].prefix << 12) | (u32)(threadIdx.x * 16 + i);
          st[sel].k = k - cum;
          break;
        }
        cum += loc[i];
      }
    }
    __syncthreads();
  }
  if (last && threadIdx.x == 0) {
    float a = __uint_as_float(st[0].prefix);
    float b = __uint_as_float(st[1].prefix);
    tval[0] = __fadd_rn(a, __fmul_rn(__fsub_rn(b, a), frac));
  }
  for (int i = threadIdx.x; i < 2 * KRADIX; i += 256) hist[i] = 0;
}

// ---------- mask -> compacted edge list + endpoint counts (+ fused label init) ----------
__global__ void __launch_bounds__(1024) k_compact(
    const float* __restrict__ score, const float* __restrict__ tval,
    const int* __restrict__ ei, int* __restrict__ selCount,
    int* __restrict__ selSrc, int* __restrict__ selDst,
    float* __restrict__ selW, int* __restrict__ cnt, int* __restrict__ labels) {
  __shared__ int wbase[16];
  int j = blockIdx.x * 1024 + threadIdx.x;
  if (j < NN) labels[j] = j;            // fused union-find init
  int lane = threadIdx.x & 63;
  int wid = threadIdx.x >> 6;
  float sc = 0.0f;
  bool sel = false;
  if (j < EE) { sc = score[j]; sel = (sc > tval[0]); }
  u64 m = __ballot(sel);
  int wcnt = __popcll(m);
  int rank = __popcll(m & ((1ULL << lane) - 1ULL));
  if (lane == 0) wbase[wid] = wcnt;
  __syncthreads();
  if (threadIdx.x == 0) {
    int tot = 0;
#pragma unroll
    for (int w = 0; w < 16; w++) tot += wbase[w];
    int base = tot ? atomicAdd(selCount, tot) : 0;
#pragma unroll
    for (int w = 0; w < 16; w++) { int c = wbase[w]; wbase[w] = base; base += c; }
  }
  __syncthreads();
  if (sel) {
    int s = ei[j], d = ei[EE + j];
    int pos = wbase[wid] + rank;
    if (pos < CAP) { selSrc[pos] = s; selDst[pos] = d; selW[pos] = sc; }
    atomicAdd(&cnt[s], 1);
    atomicAdd(&cnt[d], 1);
  }
}

// ---------- connected components: lock-free union-find (validated r7-r11) ----------
__device__ inline int uf_find(int* parent, int x) {
  while (true) {
    int p = parent[x];
    if (p == x) return x;
    int gp = parent[p];
    if (gp == p) return p;
    parent[x] = gp;           // path halving (benign race)
    x = gp;
  }
}

__global__ void k_ufUnion(const int* __restrict__ selSrc, const int* __restrict__ selDst,
                          const int* __restrict__ selCount, int* __restrict__ parent) {
  int n = selCount[0]; if (n > CAP) n = CAP;
  for (int e = blockIdx.x * 256 + threadIdx.x; e < n; e += gridDim.x * 256) {
    int ru = uf_find(parent, selSrc[e]);
    int rv = uf_find(parent, selDst[e]);
    while (ru != rv) {
      if (ru < rv) { int t = ru; ru = rv; rv = t; }
      int old = atomicCAS(&parent[ru], ru, rv);
      if (old == ru) break;
      ru = uf_find(parent, old);
      rv = uf_find(parent, rv);
    }
  }
}

// flatten + emit root flags (fused)
__global__ void k_ufFlattenRoots(int* __restrict__ parent, int* __restrict__ roots) {
  int i = blockIdx.x * 256 + threadIdx.x;
  if (i >= NN) return;
  int x = i;
  while (true) { int p = parent[x]; if (p == x) break; x = p; }
  parent[i] = x;
  roots[i] = (x == i) ? 1 : 0;
}

// cluster id + rootNode map (fused)
__global__ void k_clusterRoot(const int* __restrict__ labels, const int* __restrict__ rootScan,
                              int* __restrict__ cluster, int* __restrict__ rootNode) {
  int i = blockIdx.x * 256 + threadIdx.x;
  if (i >= NN) return;
  int cl = rootScan[labels[i]];
  cluster[i] = cl;
  if (labels[i] == i) rootNode[cl] = i;
}

// ---------- generic exclusive scan (3-launch, validated) ----------
__global__ void k_scanBlock(const int* __restrict__ src, int* __restrict__ dst,
                            int n, int* __restrict__ bsums) {
  __shared__ int part[256];
  int base = blockIdx.x * SCTILE + threadIdx.x * 8;
  int v[8]; int s = 0;
#pragma unroll
  for (int i = 0; i < 8; i++) { v[i] = (base + i < n) ? src[base + i] : 0; s += v[i]; }
  part[threadIdx.x] = s;
  __syncthreads();
  for (int off = 1; off < 256; off <<= 1) {
    int t = (threadIdx.x >= off) ? part[threadIdx.x - off] : 0;
    __syncthreads();
    part[threadIdx.x] += t;
    __syncthreads();
  }
  int run = part[threadIdx.x] - s;
#pragma unroll
  for (int i = 0; i < 8; i++) { int vv = v[i]; if (base + i < n) dst[base + i] = run; run += vv; }
  if (threadIdx.x == 255) bsums[blockIdx.x] = part[255];
}
// flag-scan fusion: flags computed inline from sorted keys
__global__ void k_scanFlags(const u32* __restrict__ keys, int* __restrict__ dst,
                            int n, int* __restrict__ bsums) {
  __shared__ int part[256];
  int base = blockIdx.x * SCTILE + threadIdx.x * 8;
  int v[8]; int s = 0;
#pragma unroll
  for (int i = 0; i < 8; i++) {
    int j = base + i;
    v[i] = (j < n) ? ((j == 0 || keys[j] != keys[j - 1]) ? 1 : 0) : 0;
    s += v[i];
  }
  part[threadIdx.x] = s;
  __syncthreads();
  for (int off = 1; off < 256; off <<= 1) {
    int t = (threadIdx.x >= off) ? part[threadIdx.x - off] : 0;
    __syncthreads();
    part[threadIdx.x] += t;
    __syncthreads();
  }
  int run = part[threadIdx.x] - s;
#pragma unroll
  for (int i = 0; i < 8; i++) { int vv = v[i]; if (base + i < n) dst[base + i] = run; run += vv; }
  if (threadIdx.x == 255) bsums[blockIdx.x] = part[255];
}
__global__ void k_scanTop(int* __restrict__ bsums, int nb) {
  __shared__ int part[256];
  int base = threadIdx.x * 4;
  int v[4]; int s = 0;
#pragma unroll
  for (int i = 0; i < 4; i++) { v[i] = (base + i < nb) ? bsums[base + i] : 0; s += v[i]; }
  part[threadIdx.x] = s;
  __syncthreads();
  for (int off = 1; off < 256; off <<= 1) {
    int t = (threadIdx.x >= off) ? part[threadIdx.x - off] : 0;
    __syncthreads();
    part[threadIdx.x] += t;
    __syncthreads();
  }
  int run = part[threadIdx.x] - s;
#pragma unroll
  for (int i = 0; i < 4; i++) { int vv = v[i]; if (base + i < nb) bsums[base + i] = run; run += vv; }
}
__global__ void k_scanAdd(int* __restrict__ data, int n, const int* __restrict__ bsums) {
  int add = bsums[blockIdx.x];
  int base = blockIdx.x * SCTILE + threadIdx.x * 8;
#pragma unroll
  for (int i = 0; i < 8; i++) if (base + i < n) data[base + i] += add;
}

// ---------- radix sort (templated key type + digit width + tile) ----------
template <typename K, int BITS, int TILE>
__global__ void k_sortHistT(const K* __restrict__ keys, int* __restrict__ hist,
                            int shift, int nb) {
  const int RAD = 1 << BITS;
  __shared__ int h[RAD];
  for (int i = threadIdx.x; i < RAD; i += 256) h[i] = 0;
  __syncthreads();
  int base = blockIdx.x * TILE;
  for (int i = threadIdx.x; i < TILE; i += 256) {
    int d = (int)((keys[base + i] >> shift) & (RAD - 1));
    atomicAdd(&h[d], 1);
  }
  __syncthreads();
  for (int i = threadIdx.x; i < RAD; i += 256) hist[i * nb + blockIdx.x] = h[i];
}

template <typename K, int BITS, int TILE>
__global__ void k_sortScatterT(const K* __restrict__ in, K* __restrict__ out,
                               const int* __restrict__ histScanned, int shift, int nb) {
  const int RAD = 1 << BITS;
  const int CH = TILE / 256;
  __shared__ int run[RAD];
  for (int i = threadIdx.x; i < RAD; i += 256) run[i] = 0;
  __syncthreads();
  int lane = threadIdx.x & 63;
  int wid = threadIdx.x >> 6;
  int base = blockIdx.x * TILE;
  for (int chunk = 0; chunk < CH; chunk++) {
    K key = in[base + chunk * 256 + threadIdx.x];
    int d = (int)((key >> shift) & (RAD - 1));
    u64 m = ~0ULL;
#pragma unroll
    for (int b = 0; b < BITS; b++) {
      u64 bal = __ballot((d >> b) & 1);
      m &= ((d >> b) & 1) ? bal : ~bal;
    }
    int laneRank = __popcll(m & ((1ULL << lane) - 1ULL));
    int cntm = __popcll(m);
    bool leader = (laneRank == 0);
    int local = 0;
    for (int w = 0; w < 4; w++) {
      if (wid == w) {
        int basev = run[d];
        local = basev + laneRank;
        if (leader) run[d] = basev + cntm;
      }
      __syncthreads();
    }
    out[histScanned[d * nb + blockIdx.x] + local] = key;
  }
}

// ---------- selected-edge keys: (cluster<<16)|e (cluster[src]==cluster[dst]) ----------
__global__ void k_ekeys(const int* __restrict__ selSrc, const int* __restrict__ cluster,
                        const int* __restrict__ selCount, u64* __restrict__ keys) {
  int t = blockIdx.x * 256 + threadIdx.x;
  if (t >= EK_N) return;
  int n = selCount[0]; if (n > EK_N) n = EK_N;
  keys[t] = (t < n) ? (((u64)(u32)cluster[selSrc[t]] << 16) | (u32)t) : ~0ULL;
}

// ---------- cluster sum, EDGE-centric: each edge visited once (2 row-reads) ----------
// cluster contribution of edge e = round(r/cnt[s]*XS) + round(r/cnt[d]*XS) --
// identical integer set as the validated per-endpoint version => bitwise-same accX.
__global__ void __launch_bounds__(128) k_clusterSum2(
    const u64* __restrict__ ek, const int* __restrict__ selSrc,
    const int* __restrict__ selDst, const float* __restrict__ selW,
    const int* __restrict__ cnt, const float* __restrict__ x, int* __restrict__ accX) {
  int c = threadIdx.x;               // channel 0..127
  int base = blockIdx.x * ECHUNK;
  u64 kc = ek[base];
  if (kc == ~0ULL) return;           // pure padding block
  int cc = (int)(kc >> 16);
  int e0 = (int)(kc & 0xFFFF);
  int s0 = selSrc[e0], d0 = selDst[e0];
  float wN = selW[e0];
  float xsN = x[(size_t)s0 * CF + c];
  float xdN = x[(size_t)d0 * CF + c];
  int csN = cnt[s0], cdN = cnt[d0];
  int curCl = cc;
  int acc = 0;
  int end = base + ECHUNK;
  for (int m = base; m < end; m++) {
    int cl = cc; float w = wN, xs = xsN, xd = xdN; int cs = csN, cd = cdN;
    bool last = true;
    if (m + 1 < end) {               // prefetch next edge (keys+rows+cnts)
      u64 kn = ek[m + 1];
      if (kn != ~0ULL) {
        last = false;
        cc = (int)(kn >> 16);
        int e1 = (int)(kn & 0xFFFF);
        int s1 = selSrc[e1], d1 = selDst[e1];
        wN = selW[e1];
        xsN = x[(size_t)s1 * CF + c];
        xdN = x[(size_t)d1 * CF + c];
        csN = cnt[s1]; cdN = cnt[d1];
      }
    }
    if (cl != curCl) {
      if (acc != 0) atomicAdd(&accX[(size_t)curCl * CF + c], acc);
      curCl = cl; acc = 0;
    }
    float r = (xs + xd) * w;
    acc += __float2int_rn((r / (float)cs) * XSCALE)
         + __float2int_rn((r / (float)cd) * XSCALE);
    if (last) break;
  }
  if (acc != 0) atomicAdd(&accX[(size_t)curCl * CF + c], acc);
}

// ---------- fused finalize: accX -> f32, singleton rows exact-copied, padding zeroed ----------
__global__ void k_finalFused(const float* __restrict__ x, const int* __restrict__ cnt,
                             const int* __restrict__ rootNode, const int* __restrict__ accX,
                             float* __restrict__ outNewX) {
  int t = (blockIdx.x * 256 + threadIdx.x) * 4;
  if (t >= NN * CF) return;
  int cl = t >> 7; int c = t & 127;
  int r = rootNode[cl];               // -1 for padding rows (0xFF memset)
  float4 o;
  if (r < 0) {
    o.x = o.y = o.z = o.w = 0.0f;
  } else if (cnt[r] == 0) {
    const float* xr = x + (size_t)r * CF + c;
    o.x = xr[0]; o.y = xr[1]; o.z = xr[2]; o.w = xr[3];
  } else {
    int4 v = *(const int4*)(accX + t);
    o.x = (float)v.x * XINV; o.y = (float)v.y * XINV;
    o.z = (float)v.z * XINV; o.w = (float)v.w * XINV;
  }
  *(float4*)(outNewX + t) = o;
}

// ---------- edge coalescing: int32-WRAPPED u32 keys (JAX x64-disabled semantics) ----------
__global__ void k_keysInit(const int* __restrict__ ei, const int* __restrict__ cluster,
                           u32* __restrict__ keys) {
  int t = blockIdx.x * 256 + threadIdx.x;
  if (t >= SORT_N) return;
  if (t < EE) {
    u32 kw = (u32)cluster[ei[t]] * 100000u + (u32)cluster[ei[EE + t]];  // int32 wraparound
    keys[t] = kw ^ 0x80000000u;   // bias: unsigned order == signed order
  } else {
    keys[t] = 0xFFFFFFFFu;        // pads sort to the tail
  }
}

// scatter of uniques; wrapped-negative uniques (front ranks) emit (-1,-1)
__global__ void k_eiScatter(const u32* __restrict__ keys, const int* __restrict__ pos,
                            float* __restrict__ outEI) {
  int j = blockIdx.x * 256 + threadIdx.x;
  if (j >= EE) return;
  bool f = (j == 0 || keys[j] != keys[j - 1]);
  if (f) {
    int p = pos[j];
    int k32 = (int)(keys[j] ^ 0x80000000u);  // unbias -> wrapped int32 key
    if (k32 >= 0) {                           // ref: valid = keys >= 0
      outEI[p] = (float)(k32 / 100000);
      outEI[EE + p] = (float)(k32 % 100000);
    } else {
      outEI[p] = -1.0f;
      outEI[EE + p] = -1.0f;
    }
  }
}
// fill tail [U, EE) with -1 (U = total uniques, from scan result)
__global__ void k_eiTail(const int* __restrict__ fscan, const u32* __restrict__ keys,
                         float* __restrict__ outEI) {
  __shared__ int sU;
  if (threadIdx.x == 0)
    sU = fscan[EE - 1] + ((keys[EE - 1] != keys[EE - 2]) ? 1 : 0);
  __syncthreads();
  int U = sU;
  int p = blockIdx.x * 256 + threadIdx.x;
  if (p < EE && p >= U) { outEI[p] = -1.0f; outEI[EE + p] = -1.0f; }
}

// ---------------------------------------------------------------------------

static inline void runScan(int* data, int n, int* bsums, hipStream_t stream) {
  int nb = (n + SCTILE - 1) / SCTILE;
  k_scanBlock<<<nb, 256, 0, stream>>>(data, data, n, bsums);
  k_scanTop<<<1, 256, 0, stream>>>(bsums, nb);
  k_scanAdd<<<nb, 256, 0, stream>>>(data, n, bsums);
}

extern "C" void kernel_launch(void* const* d_in, const int* in_sizes, int n_in,
                              void* d_out, int out_size, void* d_ws, size_t ws_size,
                              hipStream_t stream) {
  const float* x = (const float*)d_in[0];
  const int* ei = (const int*)d_in[1];
  // d_in[2] = batch (all zeros, unused)
  const float* W = (const float*)d_in[3];
  const float* bptr = (const float*)d_in[4];

  // ---- workspace carve-up (256B aligned) ----
  char* wp = (char*)d_ws;
  auto alloc = [&](size_t bytes) -> void* {
    void* r = (void*)wp;
    wp += (bytes + 255) & ~(size_t)255;
    return r;
  };
  // Overlay region (all dead before accX memset):
  double* ez = (double*)alloc((size_t)EE * 8);           // 6.4 MB
  u32* sortA = (u32*)alloc((size_t)SORT_N * 4);          // 3.2 MB
  u32* sortB = (u32*)alloc((size_t)SORT_N * 4);          // 3.2 MB
  int* histG = (int*)alloc((size_t)HISTG_LEN * 4);       // 1.6 MB
  int* fscan = (int*)alloc((size_t)EE * 4);              // 3.2 MB (also reused as roots)
  double* p_d = (double*)alloc((size_t)NN * 8);
  double* q_d = (double*)alloc((size_t)NN * 8);
  u64* menc = (u64*)alloc((size_t)NN * 8);               // zero region A start
  u64* sdenFx = (u64*)alloc((size_t)NN * 8);             // zero region A end
  char* zeroAEnd = wp;
  // accX (51.2MB) overlays everything above (~20MB)
  int* accX = (int*)d_ws;
  const size_t ACCX_BYTES = (size_t)NN * CF * 4;
  if (wp < (char*)d_ws + ACCX_BYTES) wp = (char*)d_ws + ACCX_BYTES;
  // Persistent:
  int* cnt = (int*)alloc((size_t)NN * 4);                // zero region B start
  int* selCount = (int*)alloc(256);                      // zero region B end
  char* zeroBStart = (char*)cnt; char* zeroBEnd = wp;
  int* rootNode = (int*)alloc((size_t)NN * 4);           // 0xFF memset (-1)
  int* selSrc = (int*)alloc((size_t)CAP * 4);
  int* selDst = (int*)alloc((size_t)CAP * 4);
  float* selW = (float*)alloc((size_t)CAP * 4);
  int* labels = (int*)alloc((size_t)NN * 4);
  int* cluster = (int*)alloc((size_t)NN * 4);
  u64* ekA = (u64*)alloc((size_t)EK_N * 8);              // edge-key sort (persistent)
  u64* ekB = (u64*)alloc((size_t)EK_N * 8);
  int* bsums = (int*)alloc(1024 * 4);
  Sel* st = (Sel*)alloc(256);
  u32* selHist = (u32*)alloc((size_t)2 * KRADIX * 4);
  float* tval = (float*)alloc(256);
  (void)ws_size; (void)n_in; (void)in_sizes;

  // ---- output regions (all written as f32) ----
  float* outNewX = (float*)d_out;                       // N*C
  float* outEI = outNewX + (size_t)NN * CF;             // 2*E
  float* outBatch = outEI + 2 * (size_t)EE;             // N (zeros via memset)
  float* outScore = outBatch + NN;                      // E

  // ---- quantile index/weights (np.quantile: virtual index) ----
  double qd = 1.0 - (double)(NN / 2) / (double)EE;      // 0.9375 exact
  double posd = qd * (double)(EE - 1);                  // 749999.0625 exact
  int k0 = (int)floor(posd);
  double fracd = posd - floor(posd);                    // 0.0625 exact
  int k1 = (fracd > 0.0) ? k0 + 1 : k0;
  float frac = (float)fracd;

  // ---- init ----
  hipMemsetAsync(outBatch, 0, (size_t)NN * 4, stream);
  hipMemsetAsync(menc, 0, (size_t)(zeroAEnd - (char*)menc), stream);
  hipMemsetAsync(zeroBStart, 0, (size_t)(zeroBEnd - zeroBStart), stream);
  hipMemsetAsync(rootNode, 0xFF, (size_t)NN * 4, stream);   // -1 sentinel

  // ---- scores (deterministic: f64 math + exact max + fixed-point denom) ----
  k_pq<<<(NN + 3) / 4, 256, 0, stream>>>(x, W, p_d, q_d);
  k_em<<<(EE + 255) / 256, 256, 0, stream>>>(ei, p_d, q_d, bptr, ez, menc);
  k_zs<<<(EE + 255) / 256, 256, 0, stream>>>(ei, ez, menc, sdenFx);
  k_score<<<(EE + 255) / 256, 256, 0, stream>>>(ei, ez, sdenFx, outScore);

  // ---- quantile via radix select (2 x 12-bit passes; top byte known = 0x3F) ----
  k_selInit<<<(2 * KRADIX + 255) / 256, 256, 0, stream>>>(st, selHist, k0, k1);
  for (int pass = 0; pass < 2; pass++) {
    k_selHist12<<<1024, 256, 0, stream>>>(outScore, st, selHist, 12 - 12 * pass);
    k_selPick12<<<1, 256, 0, stream>>>(st, selHist, tval, frac, pass == 1);
  }

  // ---- mask -> compacted edges + endpoint counts (+ label init) ----
  k_compact<<<(EE + 1023) / 1024, 1024, 0, stream>>>(outScore, tval, ei, selCount,
                                                     selSrc, selDst, selW, cnt, labels);

  // ---- connected components: lock-free union-find ----
  k_ufUnion<<<256, 256, 0, stream>>>(selSrc, selDst, selCount, labels);
  k_ufUnion<<<256, 256, 0, stream>>>(selSrc, selDst, selCount, labels);  // belt-and-braces
  k_ufFlattenRoots<<<(NN + 255) / 256, 256, 0, stream>>>(labels, fscan);

  // ---- relabel by rank of component-min ----
  runScan(fscan, NN, bsums, stream);
  k_clusterRoot<<<(NN + 255) / 256, 256, 0, stream>>>(labels, fscan, cluster, rootNode);

  // ---- selected-edge keys sorted by cluster (2 x 12-bit passes over cluster bits) ----
  k_ekeys<<<EK_N / 256, 256, 0, stream>>>(selSrc, cluster, selCount, ekA);
  {
    u64* kin = ekA; u64* kout = ekB;
    for (int pass = 0; pass < 2; pass++) {
      int shift = 16 + KBITS * pass;
      k_sortHistT<u64, KBITS, KTILE><<<NB_EK, 256, 0, stream>>>(kin, histG, shift, NB_EK);
      runScan(histG, KRADIX * NB_EK, bsums, stream);
      k_sortScatterT<u64, KBITS, KTILE><<<NB_EK, 256, 0, stream>>>(kin, kout, histG, shift, NB_EK);
      u64* tmp = kin; kin = kout; kout = tmp;
    }
    // 2 passes: ekA -> ekB -> ekA; result in ekA (persistent)
  }

  // ---- coalesced cluster edges: u32 keys, 3 x 11-bit passes, tile 4096 ----
  k_keysInit<<<SORT_N / 256, 256, 0, stream>>>(ei, cluster, sortA);
  u32* sin = sortA; u32* sout = sortB;
  for (int pass = 0; pass < 3; pass++) {
    int shift = EBITS * pass;
    k_sortHistT<u32, EBITS, ETILE><<<NB_E, 256, 0, stream>>>(sin, histG, shift, NB_E);
    runScan(histG, ERADIX * NB_E, bsums, stream);
    k_sortScatterT<u32, EBITS, ETILE><<<NB_E, 256, 0, stream>>>(sin, sout, histG, shift, NB_E);
    u32* tmp = sin; sin = sout; sout = tmp;
  }
  // result in sortB (== sin)
  {
    int nb = (EE + SCTILE - 1) / SCTILE;
    k_scanFlags<<<nb, 256, 0, stream>>>(sin, fscan, EE, bsums);
    k_scanTop<<<1, 256, 0, stream>>>(bsums, nb);
    k_scanAdd<<<nb, 256, 0, stream>>>(fscan, EE, bsums);
  }
  k_eiScatter<<<(EE + 255) / 256, 256, 0, stream>>>(sin, fscan, outEI);
  k_eiTail<<<(EE + 255) / 256, 256, 0, stream>>>(fscan, sin, outEI);

  // ---- new_x: edge-centric segmented sum (overlay now safe) ----
  hipMemsetAsync(accX, 0, ACCX_BYTES, stream);
  k_clusterSum2<<<EK_N / ECHUNK, 128, 0, stream>>>(ekA, selSrc, selDst, selW, cnt, x, accX);
  k_finalFused<<<(NN * CF / 4 + 255) / 256, 256, 0, stream>>>(x, cnt, rootNode, accX, outNewX);
}